// Round 1
// baseline (2005.219 us; speedup 1.0000x reference)
//
#include <hip/hip_runtime.h>
#include <hip/hip_bf16.h>

// Shapes (fixed): B=2, L=2048, DIM=1024, D_INNER=2048, DT_RANK=64, D_STATE=16, D_CONV=4
// Inputs order: x, gamma, beta, W_in, conv_w, conv_b, W_xproj, W_dt, b_dt, A_log, D, W_out
// ws layout (floats):
//   xn    @ 0          : 4096*1024
//   xz    @ 4194304    : 4096*4096   (u_raw = [:, :2048], z = [:, 2048:]; scan overwrites u_raw with gated y)
//   u     @ 20971520   : 4096*2048   (post conv+silu)
//   xdbl  @ 29360128   : 4096*96     (dt|B|C)
//   delta @ 29753344   : 4096*2048
// total 38,141,952 floats = 152.6 MB

#define ROWS 4096   // B*L
#define DIM 1024
#define DINNER 2048
#define LSEQ 2048

__global__ __launch_bounds__(256) void ln_kernel(const float* __restrict__ x,
    const float* __restrict__ gamma, const float* __restrict__ beta,
    float* __restrict__ xn)
{
    const int row = blockIdx.x;
    const int tid = threadIdx.x;
    float4 v = ((const float4*)(x + (long)row * DIM))[tid];
    float s  = v.x + v.y + v.z + v.w;
    float sq = v.x*v.x + v.y*v.y + v.z*v.z + v.w*v.w;
    #pragma unroll
    for (int off = 32; off > 0; off >>= 1) {
        s  += __shfl_down(s,  off, 64);
        sq += __shfl_down(sq, off, 64);
    }
    __shared__ float ss[8], ssq[8];
    const int wid = tid >> 6, lane = tid & 63;
    if (lane == 0) { ss[wid] = s; ssq[wid] = sq; }
    __syncthreads();
    if (tid == 0) {
        float S = 0.f, SQ = 0.f;
        for (int w = 0; w < 4; ++w) { S += ss[w]; SQ += ssq[w]; }
        float mu  = S / (float)DIM;
        float var = SQ / (float)DIM - mu * mu;
        ss[4]  = mu;
        ssq[4] = rsqrtf(var + 1e-5f);
    }
    __syncthreads();
    const float mu = ss[4], rs = ssq[4];
    float4 g = ((const float4*)gamma)[tid];
    float4 b = ((const float4*)beta)[tid];
    float4 o;
    o.x = (v.x - mu) * rs * g.x + b.x;
    o.y = (v.y - mu) * rs * g.y + b.y;
    o.z = (v.z - mu) * rs * g.z + b.z;
    o.w = (v.w - mu) * rs * g.w + b.w;
    ((float4*)(xn + (long)row * DIM))[tid] = o;
}

// C[M,N] = A[M,K] @ B[K,N] (+ resid). BM=BN=128, BK=8, 256 threads, 8x8 per thread.
__global__ __launch_bounds__(256) void gemm128(
    const float* __restrict__ A, int lda,
    const float* __restrict__ B, int ldb,
    float* __restrict__ C, int ldc,
    const float* __restrict__ resid, int ldr,
    int K)
{
    __shared__ float As[8][128];
    __shared__ float Bs[8][128];
    const int tid = threadIdx.x;
    const int tx = tid & 15, ty = tid >> 4;
    const long row0 = (long)blockIdx.y * 128, col0 = (long)blockIdx.x * 128;
    const int ar = tid >> 1, ac = (tid & 1) * 4;
    const int br = tid >> 5, bc = (tid & 31) * 4;
    const float* Ap = A + (row0 + ar) * (long)lda + ac;
    const float* Bp = B + (long)br * ldb + col0 + bc;
    float acc[8][8];
    #pragma unroll
    for (int i = 0; i < 8; ++i)
        #pragma unroll
        for (int j = 0; j < 8; ++j) acc[i][j] = 0.f;

    for (int k0 = 0; k0 < K; k0 += 8) {
        float4 av = *(const float4*)(Ap + k0);
        float4 bv = *(const float4*)(Bp + (long)k0 * ldb);
        __syncthreads();
        As[ac+0][ar] = av.x;
        As[ac+1][ar] = av.y;
        As[ac+2][ar] = av.z;
        As[ac+3][ar] = av.w;
        *(float4*)&Bs[br][bc] = bv;
        __syncthreads();
        #pragma unroll
        for (int k = 0; k < 8; ++k) {
            float4 a0 = *(const float4*)&As[k][ty*8];
            float4 a1 = *(const float4*)&As[k][ty*8+4];
            float4 b0 = *(const float4*)&Bs[k][tx*8];
            float4 b1 = *(const float4*)&Bs[k][tx*8+4];
            float a[8] = {a0.x,a0.y,a0.z,a0.w,a1.x,a1.y,a1.z,a1.w};
            float b[8] = {b0.x,b0.y,b0.z,b0.w,b1.x,b1.y,b1.z,b1.w};
            #pragma unroll
            for (int i = 0; i < 8; ++i)
                #pragma unroll
                for (int j = 0; j < 8; ++j)
                    acc[i][j] = fmaf(a[i], b[j], acc[i][j]);
        }
    }
    #pragma unroll
    for (int i = 0; i < 8; ++i) {
        long r = row0 + ty*8 + i;
        long c = col0 + tx*8;
        #pragma unroll
        for (int j4 = 0; j4 < 2; ++j4) {
            float4 v = make_float4(acc[i][j4*4+0], acc[i][j4*4+1],
                                   acc[i][j4*4+2], acc[i][j4*4+3]);
            if (resid) {
                float4 rv = *(const float4*)(resid + r * (long)ldr + c + j4*4);
                v.x += rv.x; v.y += rv.y; v.z += rv.z; v.w += rv.w;
            }
            *(float4*)(C + r * (long)ldc + c + j4*4) = v;
        }
    }
}

// u[b,l,d] = silu( sum_k cw[d,k]*u_raw[b,l-3+k,d] + cb[d] ); u_raw = xz[:, :2048]
__global__ __launch_bounds__(256) void conv_silu(
    const float* __restrict__ xz, const float* __restrict__ cw,
    const float* __restrict__ cb, float* __restrict__ uo)
{
    const int t = blockIdx.x * 256 + threadIdx.x;   // 0 .. B*L*512-1
    const int dq = t & 511;
    const int l  = (t >> 9) & 2047;
    const int b  = t >> 20;
    const int d  = dq * 4;
    const float4* w4 = (const float4*)(cw + (long)d * 4);
    float4 w0 = w4[0], w1 = w4[1], w2 = w4[2], w3 = w4[3];
    const float* wr[4] = { (const float*)&w0, (const float*)&w1,
                           (const float*)&w2, (const float*)&w3 };
    float4 bias = *(const float4*)(cb + d);
    float acc0 = bias.x, acc1 = bias.y, acc2 = bias.z, acc3 = bias.w;
    const float* base = xz + ((long)b * LSEQ) * 4096 + d;
    #pragma unroll
    for (int k = 0; k < 4; ++k) {
        int ls = l - 3 + k;
        if (ls >= 0) {
            float4 tv = *(const float4*)(base + (long)ls * 4096);
            acc0 = fmaf(wr[0][k], tv.x, acc0);
            acc1 = fmaf(wr[1][k], tv.y, acc1);
            acc2 = fmaf(wr[2][k], tv.z, acc2);
            acc3 = fmaf(wr[3][k], tv.w, acc3);
        }
    }
    float4 o;
    o.x = acc0 / (1.f + __expf(-acc0));
    o.y = acc1 / (1.f + __expf(-acc1));
    o.z = acc2 / (1.f + __expf(-acc2));
    o.w = acc3 / (1.f + __expf(-acc3));
    *(float4*)(uo + ((long)b * LSEQ + l) * DINNER + d) = o;
}

// xdbl[row, 0:96] = u[row, :] @ W_xproj[2048, 96]
__global__ __launch_bounds__(128) void xproj_kernel(
    const float* __restrict__ u, const float* __restrict__ Wx,
    float* __restrict__ xdbl)
{
    __shared__ float us[DINNER];
    const int row = blockIdx.x;
    const float* ur = u + (long)row * DINNER;
    for (int i = threadIdx.x; i < DINNER/4; i += 128)
        ((float4*)us)[i] = ((const float4*)ur)[i];
    __syncthreads();
    const int j = threadIdx.x;
    if (j < 96) {
        float acc = 0.f;
        #pragma unroll 8
        for (int k = 0; k < DINNER; ++k)
            acc = fmaf(us[k], Wx[(long)k * 96 + j], acc);
        xdbl[(long)row * 96 + j] = acc;
    }
}

// delta[row, d] = softplus( xdbl[row,0:64] @ W_dt[64,2048] + b_dt )
__global__ __launch_bounds__(256) void dtproj_kernel(
    const float* __restrict__ xdbl, const float* __restrict__ Wdt,
    const float* __restrict__ bdt, float* __restrict__ delta)
{
    __shared__ float dts[64];
    const int row = blockIdx.x;
    if (threadIdx.x < 64) dts[threadIdx.x] = xdbl[(long)row * 96 + threadIdx.x];
    __syncthreads();
    #pragma unroll
    for (int rep = 0; rep < 8; ++rep) {
        const int d = threadIdx.x + rep * 256;
        float acc = bdt[d];
        #pragma unroll 8
        for (int k = 0; k < 64; ++k)
            acc = fmaf(dts[k], Wdt[(long)k * DINNER + d], acc);
        float sp = (acc > 20.f) ? acc : log1pf(__expf(acc));
        delta[(long)row * DINNER + d] = sp;
    }
}

// Sequential selective scan + skip + gate. Writes gated y into xz[:, :2048].
__global__ __launch_bounds__(256) void scan_kernel(
    const float* __restrict__ u, const float* __restrict__ delta,
    const float* __restrict__ xdbl, const float* __restrict__ A_log,
    const float* __restrict__ Dp, float* __restrict__ xz)
{
    const int d = blockIdx.x * 256 + threadIdx.x;
    const int b = blockIdx.y;
    float A[16];
    #pragma unroll
    for (int s = 0; s < 16; ++s) A[s] = -__expf(A_log[(long)d * 16 + s]);
    const float Dd = Dp[d];
    float h[16];
    #pragma unroll
    for (int s = 0; s < 16; ++s) h[s] = 0.f;
    const float* ub = u     + ((long)b * LSEQ) * DINNER + d;
    const float* db = delta + ((long)b * LSEQ) * DINNER + d;
    const float* xb = xdbl  + ((long)b * LSEQ) * 96 + 64;
    float* zy = xz + ((long)b * LSEQ) * 4096;

    for (int t = 0; t < LSEQ; ++t) {
        float dt = db[(long)t * DINNER];
        float ut = ub[(long)t * DINNER];
        float zt = zy[(long)t * 4096 + 2048 + d];
        const float4* bc4 = (const float4*)(xb + (long)t * 96);
        float4 B0 = bc4[0], B1 = bc4[1], B2 = bc4[2], B3 = bc4[3];
        float4 C0 = bc4[4], C1 = bc4[5], C2 = bc4[6], C3 = bc4[7];
        float Bv[16], Cv[16];
        Bv[0]=B0.x; Bv[1]=B0.y; Bv[2]=B0.z; Bv[3]=B0.w;
        Bv[4]=B1.x; Bv[5]=B1.y; Bv[6]=B1.z; Bv[7]=B1.w;
        Bv[8]=B2.x; Bv[9]=B2.y; Bv[10]=B2.z; Bv[11]=B2.w;
        Bv[12]=B3.x; Bv[13]=B3.y; Bv[14]=B3.z; Bv[15]=B3.w;
        Cv[0]=C0.x; Cv[1]=C0.y; Cv[2]=C0.z; Cv[3]=C0.w;
        Cv[4]=C1.x; Cv[5]=C1.y; Cv[6]=C1.z; Cv[7]=C1.w;
        Cv[8]=C2.x; Cv[9]=C2.y; Cv[10]=C2.z; Cv[11]=C2.w;
        Cv[12]=C3.x; Cv[13]=C3.y; Cv[14]=C3.z; Cv[15]=C3.w;
        const float du = dt * ut;
        float y = 0.f;
        #pragma unroll
        for (int s = 0; s < 16; ++s) {
            h[s] = fmaf(h[s], __expf(dt * A[s]), du * Bv[s]);
            y = fmaf(h[s], Cv[s], y);
        }
        y = fmaf(ut, Dd, y);
        float sig = 1.f / (1.f + __expf(-zt));
        zy[(long)t * 4096 + d] = y * (zt * sig);
    }
}

extern "C" void kernel_launch(void* const* d_in, const int* in_sizes, int n_in,
                              void* d_out, int out_size, void* d_ws, size_t ws_size,
                              hipStream_t stream) {
    const float* x      = (const float*)d_in[0];
    const float* gamma  = (const float*)d_in[1];
    const float* beta   = (const float*)d_in[2];
    const float* W_in   = (const float*)d_in[3];
    const float* conv_w = (const float*)d_in[4];
    const float* conv_b = (const float*)d_in[5];
    const float* W_xp   = (const float*)d_in[6];
    const float* W_dt   = (const float*)d_in[7];
    const float* b_dt   = (const float*)d_in[8];
    const float* A_log  = (const float*)d_in[9];
    const float* Dp     = (const float*)d_in[10];
    const float* W_out  = (const float*)d_in[11];
    float* out = (float*)d_out;
    float* ws  = (float*)d_ws;

    float* xn    = ws;
    float* xz    = ws + 4194304L;
    float* u     = ws + 20971520L;
    float* xdbl  = ws + 29360128L;
    float* delta = ws + 29753344L;

    // 1. LayerNorm
    ln_kernel<<<ROWS, 256, 0, stream>>>(x, gamma, beta, xn);
    // 2. xz = xn @ W_in   [4096,1024]@[1024,4096]
    gemm128<<<dim3(32, 32), 256, 0, stream>>>(xn, DIM, W_in, 4096, xz, 4096,
                                              nullptr, 0, DIM);
    // 3. depthwise causal conv + bias + SiLU -> u
    conv_silu<<<8192, 256, 0, stream>>>(xz, conv_w, conv_b, u);
    // 4. xdbl = u @ W_xproj  [4096,2048]@[2048,96]
    xproj_kernel<<<ROWS, 128, 0, stream>>>(u, W_xp, xdbl);
    // 5. delta = softplus(dt @ W_dt + b_dt)
    dtproj_kernel<<<ROWS, 256, 0, stream>>>(xdbl, W_dt, b_dt, delta);
    // 6. selective scan + skip(D*u) + gate(silu(z)) -> xz[:, :2048]
    scan_kernel<<<dim3(8, 2), 256, 0, stream>>>(u, delta, xdbl, A_log, Dp, xz);
    // 7. out = x + y @ W_out   [4096,2048]@[2048,1024]
    gemm128<<<dim3(8, 32), 256, 0, stream>>>(xz, 4096, W_out, DIM, out, DIM,
                                             x, DIM, DINNER);
}

// Round 2
// 1026.683 us; speedup vs baseline: 1.9531x; 1.9531x over previous
//
#include <hip/hip_runtime.h>
#include <hip/hip_bf16.h>

// Shapes (fixed): B=2, L=2048, DIM=1024, D_INNER=2048, DT_RANK=64, D_STATE=16, D_CONV=4
// Inputs order: x, gamma, beta, W_in, conv_w, conv_b, W_xproj, W_dt, b_dt, A_log, D, W_out
// ws layout (floats):
//   xn    @ 0          : 4096*1024   (dead after GEMM1 -> reused: P @0 [2.1M], Hend @2097152 [2.1M])
//   xz    @ 4194304    : 4096*4096   (u_raw = [:, :2048], z = [:, 2048:]; scan writes gated y over u_raw)
//   u     @ 20971520   : 4096*2048   (post conv+silu)
//   xdbl  @ 29360128   : 4096*96     (dt|B|C)
//   delta @ 29753344   : 4096*2048
// total 38,141,952 floats = 152.6 MB

#define ROWS 4096   // B*L
#define DIM 1024
#define DINNER 2048
#define LSEQ 2048
#define NC 32       // scan chunks
#define CL 64       // chunk length (NC*CL == LSEQ)

__global__ __launch_bounds__(256) void ln_kernel(const float* __restrict__ x,
    const float* __restrict__ gamma, const float* __restrict__ beta,
    float* __restrict__ xn)
{
    const int row = blockIdx.x;
    const int tid = threadIdx.x;
    float4 v = ((const float4*)(x + (long)row * DIM))[tid];
    float s  = v.x + v.y + v.z + v.w;
    float sq = v.x*v.x + v.y*v.y + v.z*v.z + v.w*v.w;
    #pragma unroll
    for (int off = 32; off > 0; off >>= 1) {
        s  += __shfl_down(s,  off, 64);
        sq += __shfl_down(sq, off, 64);
    }
    __shared__ float ss[8], ssq[8];
    const int wid = tid >> 6, lane = tid & 63;
    if (lane == 0) { ss[wid] = s; ssq[wid] = sq; }
    __syncthreads();
    if (tid == 0) {
        float S = 0.f, SQ = 0.f;
        for (int w = 0; w < 4; ++w) { S += ss[w]; SQ += ssq[w]; }
        float mu  = S / (float)DIM;
        float var = SQ / (float)DIM - mu * mu;
        ss[4]  = mu;
        ssq[4] = rsqrtf(var + 1e-5f);
    }
    __syncthreads();
    const float mu = ss[4], rs = ssq[4];
    float4 g = ((const float4*)gamma)[tid];
    float4 b = ((const float4*)beta)[tid];
    float4 o;
    o.x = (v.x - mu) * rs * g.x + b.x;
    o.y = (v.y - mu) * rs * g.y + b.y;
    o.z = (v.z - mu) * rs * g.z + b.z;
    o.w = (v.w - mu) * rs * g.w + b.w;
    ((float4*)(xn + (long)row * DIM))[tid] = o;
}

// C[M,N] = A[M,K] @ B[K,N] (+ resid). BM=BN=128, BK=8, 256 threads, 8x8 per thread.
__global__ __launch_bounds__(256) void gemm128(
    const float* __restrict__ A, int lda,
    const float* __restrict__ B, int ldb,
    float* __restrict__ C, int ldc,
    const float* __restrict__ resid, int ldr,
    int K)
{
    __shared__ float As[8][128];
    __shared__ float Bs[8][128];
    const int tid = threadIdx.x;
    const int tx = tid & 15, ty = tid >> 4;
    const long row0 = (long)blockIdx.y * 128, col0 = (long)blockIdx.x * 128;
    const int ar = tid >> 1, ac = (tid & 1) * 4;
    const int br = tid >> 5, bc = (tid & 31) * 4;
    const float* Ap = A + (row0 + ar) * (long)lda + ac;
    const float* Bp = B + (long)br * ldb + col0 + bc;
    float acc[8][8];
    #pragma unroll
    for (int i = 0; i < 8; ++i)
        #pragma unroll
        for (int j = 0; j < 8; ++j) acc[i][j] = 0.f;

    for (int k0 = 0; k0 < K; k0 += 8) {
        float4 av = *(const float4*)(Ap + k0);
        float4 bv = *(const float4*)(Bp + (long)k0 * ldb);
        __syncthreads();
        As[ac+0][ar] = av.x;
        As[ac+1][ar] = av.y;
        As[ac+2][ar] = av.z;
        As[ac+3][ar] = av.w;
        *(float4*)&Bs[br][bc] = bv;
        __syncthreads();
        #pragma unroll
        for (int k = 0; k < 8; ++k) {
            float4 a0 = *(const float4*)&As[k][ty*8];
            float4 a1 = *(const float4*)&As[k][ty*8+4];
            float4 b0 = *(const float4*)&Bs[k][tx*8];
            float4 b1 = *(const float4*)&Bs[k][tx*8+4];
            float a[8] = {a0.x,a0.y,a0.z,a0.w,a1.x,a1.y,a1.z,a1.w};
            float b[8] = {b0.x,b0.y,b0.z,b0.w,b1.x,b1.y,b1.z,b1.w};
            #pragma unroll
            for (int i = 0; i < 8; ++i)
                #pragma unroll
                for (int j = 0; j < 8; ++j)
                    acc[i][j] = fmaf(a[i], b[j], acc[i][j]);
        }
    }
    #pragma unroll
    for (int i = 0; i < 8; ++i) {
        long r = row0 + ty*8 + i;
        long c = col0 + tx*8;
        #pragma unroll
        for (int j4 = 0; j4 < 2; ++j4) {
            float4 v = make_float4(acc[i][j4*4+0], acc[i][j4*4+1],
                                   acc[i][j4*4+2], acc[i][j4*4+3]);
            if (resid) {
                float4 rv = *(const float4*)(resid + r * (long)ldr + c + j4*4);
                v.x += rv.x; v.y += rv.y; v.z += rv.z; v.w += rv.w;
            }
            *(float4*)(C + r * (long)ldc + c + j4*4) = v;
        }
    }
}

// u[b,l,d] = silu( sum_k cw[d,k]*u_raw[b,l-3+k,d] + cb[d] ); u_raw = xz[:, :2048]
__global__ __launch_bounds__(256) void conv_silu(
    const float* __restrict__ xz, const float* __restrict__ cw,
    const float* __restrict__ cb, float* __restrict__ uo)
{
    const int t = blockIdx.x * 256 + threadIdx.x;   // 0 .. B*L*512-1
    const int dq = t & 511;
    const int l  = (t >> 9) & 2047;
    const int b  = t >> 20;
    const int d  = dq * 4;
    const float4* w4 = (const float4*)(cw + (long)d * 4);
    float4 w0 = w4[0], w1 = w4[1], w2 = w4[2], w3 = w4[3];
    const float* wr[4] = { (const float*)&w0, (const float*)&w1,
                           (const float*)&w2, (const float*)&w3 };
    float4 bias = *(const float4*)(cb + d);
    float acc0 = bias.x, acc1 = bias.y, acc2 = bias.z, acc3 = bias.w;
    const float* base = xz + ((long)b * LSEQ) * 4096 + d;
    #pragma unroll
    for (int k = 0; k < 4; ++k) {
        int ls = l - 3 + k;
        if (ls >= 0) {
            float4 tv = *(const float4*)(base + (long)ls * 4096);
            acc0 = fmaf(wr[0][k], tv.x, acc0);
            acc1 = fmaf(wr[1][k], tv.y, acc1);
            acc2 = fmaf(wr[2][k], tv.z, acc2);
            acc3 = fmaf(wr[3][k], tv.w, acc3);
        }
    }
    float4 o;
    o.x = acc0 / (1.f + __expf(-acc0));
    o.y = acc1 / (1.f + __expf(-acc1));
    o.z = acc2 / (1.f + __expf(-acc2));
    o.w = acc3 / (1.f + __expf(-acc3));
    *(float4*)(uo + ((long)b * LSEQ + l) * DINNER + d) = o;
}

// xdbl[row, 0:96] = u[row, :] @ W_xproj[2048, 96]
__global__ __launch_bounds__(128) void xproj_kernel(
    const float* __restrict__ u, const float* __restrict__ Wx,
    float* __restrict__ xdbl)
{
    __shared__ float us[DINNER];
    const int row = blockIdx.x;
    const float* ur = u + (long)row * DINNER;
    for (int i = threadIdx.x; i < DINNER/4; i += 128)
        ((float4*)us)[i] = ((const float4*)ur)[i];
    __syncthreads();
    const int j = threadIdx.x;
    if (j < 96) {
        float acc = 0.f;
        #pragma unroll 8
        for (int k = 0; k < DINNER; ++k)
            acc = fmaf(us[k], Wx[(long)k * 96 + j], acc);
        xdbl[(long)row * 96 + j] = acc;
    }
}

// delta[row, d] = softplus( xdbl[row,0:64] @ W_dt[64,2048] + b_dt )
__global__ __launch_bounds__(256) void dtproj_kernel(
    const float* __restrict__ xdbl, const float* __restrict__ Wdt,
    const float* __restrict__ bdt, float* __restrict__ delta)
{
    __shared__ float dts[64];
    const int row = blockIdx.x;
    if (threadIdx.x < 64) dts[threadIdx.x] = xdbl[(long)row * 96 + threadIdx.x];
    __syncthreads();
    #pragma unroll
    for (int rep = 0; rep < 8; ++rep) {
        const int d = threadIdx.x + rep * 256;
        float acc = bdt[d];
        #pragma unroll 8
        for (int k = 0; k < 64; ++k)
            acc = fmaf(dts[k], Wdt[(long)k * DINNER + d], acc);
        float sp = (acc > 20.f) ? acc : log1pf(__expf(acc));
        delta[(long)row * DINNER + d] = sp;
    }
}

// ---- chunked parallel scan ----
// Phase 1: per (b, chunk, d): local scan from h=0 over CL steps.
// Writes P[b][c][d][s] (cumprod of a) and Hend[b][c][d][s].
__global__ __launch_bounds__(256) void scan_p1(
    const float* __restrict__ u, const float* __restrict__ delta,
    const float* __restrict__ xdbl, const float* __restrict__ A_log,
    float* __restrict__ P, float* __restrict__ Hend)
{
    __shared__ float bsm[CL * 16];            // B values for this chunk
    const int d = blockIdx.x * 256 + threadIdx.x;
    const int c = blockIdx.y;
    const int b = blockIdx.z;
    const long rowbase = (long)b * LSEQ + (long)c * CL;
    for (int i = threadIdx.x; i < CL * 16; i += 256) {
        int t = i >> 4, s = i & 15;
        bsm[i] = xdbl[(rowbase + t) * 96 + 64 + s];
    }
    __syncthreads();
    float A[16];
    #pragma unroll
    for (int s = 0; s < 16; ++s) A[s] = -__expf(A_log[(long)d * 16 + s]);
    float h[16], p[16];
    #pragma unroll
    for (int s = 0; s < 16; ++s) { h[s] = 0.f; p[s] = 1.f; }
    const float* ub = u     + rowbase * DINNER + d;
    const float* db = delta + rowbase * DINNER + d;
    for (int t = 0; t < CL; ++t) {
        float dt = db[(long)t * DINNER];
        float du = dt * ub[(long)t * DINNER];
        const float* bv = &bsm[t * 16];
        #pragma unroll
        for (int s = 0; s < 16; ++s) {
            float a = __expf(dt * A[s]);
            p[s] *= a;
            h[s] = fmaf(h[s], a, du * bv[s]);
        }
    }
    const long o = (((long)b * NC + c) * DINNER + d) * 16;
    #pragma unroll
    for (int q = 0; q < 4; ++q) {
        *(float4*)(P    + o + q*4) = make_float4(p[q*4],p[q*4+1],p[q*4+2],p[q*4+3]);
        *(float4*)(Hend + o + q*4) = make_float4(h[q*4],h[q*4+1],h[q*4+2],h[q*4+3]);
    }
}

// Phase 2: sequential over chunks; converts Hend -> Hin in place.
// thread idx -> (b, d, s); per c: tmp=H; H=carry; carry = carry*P + tmp.
__global__ __launch_bounds__(256) void scan_p2(
    const float* __restrict__ P, float* __restrict__ H)
{
    const int idx = blockIdx.x * 256 + threadIdx.x;   // 0 .. 65535
    const int b = idx >> 15;
    const int rest = idx & 32767;                     // d*16 + s
    float carry = 0.f;
    for (int c = 0; c < NC; ++c) {
        const long a = ((long)(b * NC + c) << 15) + rest;
        float tmp = H[a];
        float pp  = P[a];
        H[a] = carry;
        carry = fmaf(carry, pp, tmp);
    }
}

// Phase 3: re-run local scan from Hin; y + D*u skip + silu(z) gate -> xz[:, :2048]
__global__ __launch_bounds__(256) void scan_p3(
    const float* __restrict__ u, const float* __restrict__ delta,
    const float* __restrict__ xdbl, const float* __restrict__ A_log,
    const float* __restrict__ Dp, const float* __restrict__ Hin,
    float* __restrict__ xz)
{
    __shared__ float bcs[CL * 32];            // B|C values for this chunk
    const int d = blockIdx.x * 256 + threadIdx.x;
    const int c = blockIdx.y;
    const int b = blockIdx.z;
    const long rowbase = (long)b * LSEQ + (long)c * CL;
    for (int i = threadIdx.x; i < CL * 32; i += 256) {
        int t = i >> 5, s = i & 31;
        bcs[i] = xdbl[(rowbase + t) * 96 + 64 + s];
    }
    __syncthreads();
    float A[16];
    #pragma unroll
    for (int s = 0; s < 16; ++s) A[s] = -__expf(A_log[(long)d * 16 + s]);
    float h[16];
    const long o = (((long)b * NC + c) * DINNER + d) * 16;
    #pragma unroll
    for (int q = 0; q < 4; ++q) {
        float4 hv = *(const float4*)(Hin + o + q*4);
        h[q*4] = hv.x; h[q*4+1] = hv.y; h[q*4+2] = hv.z; h[q*4+3] = hv.w;
    }
    const float Dd = Dp[d];
    const float* ub = u     + rowbase * DINNER + d;
    const float* db = delta + rowbase * DINNER + d;
    float* zy = xz + rowbase * 4096;
    for (int t = 0; t < CL; ++t) {
        float dt = db[(long)t * DINNER];
        float ut = ub[(long)t * DINNER];
        float zt = zy[(long)t * 4096 + 2048 + d];
        float du = dt * ut;
        const float* bv = &bcs[t * 32];
        float y = 0.f;
        #pragma unroll
        for (int s = 0; s < 16; ++s) {
            float a = __expf(dt * A[s]);
            h[s] = fmaf(h[s], a, du * bv[s]);
            y = fmaf(h[s], bv[16 + s], y);
        }
        y = fmaf(ut, Dd, y);
        float sig = 1.f / (1.f + __expf(-zt));
        zy[(long)t * 4096 + d] = y * (zt * sig);
    }
}

extern "C" void kernel_launch(void* const* d_in, const int* in_sizes, int n_in,
                              void* d_out, int out_size, void* d_ws, size_t ws_size,
                              hipStream_t stream) {
    const float* x      = (const float*)d_in[0];
    const float* gamma  = (const float*)d_in[1];
    const float* beta   = (const float*)d_in[2];
    const float* W_in   = (const float*)d_in[3];
    const float* conv_w = (const float*)d_in[4];
    const float* conv_b = (const float*)d_in[5];
    const float* W_xp   = (const float*)d_in[6];
    const float* W_dt   = (const float*)d_in[7];
    const float* b_dt   = (const float*)d_in[8];
    const float* A_log  = (const float*)d_in[9];
    const float* Dp     = (const float*)d_in[10];
    const float* W_out  = (const float*)d_in[11];
    float* out = (float*)d_out;
    float* ws  = (float*)d_ws;

    float* xn    = ws;                       // 4096*1024; dead after GEMM1
    float* P     = ws;                       // reuse xn: 2*NC*2048*16 = 2,097,152
    float* Hend  = ws + 2097152L;            // 2,097,152 (exactly fills xn)
    float* xz    = ws + 4194304L;
    float* u     = ws + 20971520L;
    float* xdbl  = ws + 29360128L;
    float* delta = ws + 29753344L;

    // 1. LayerNorm
    ln_kernel<<<ROWS, 256, 0, stream>>>(x, gamma, beta, xn);
    // 2. xz = xn @ W_in   [4096,1024]@[1024,4096]
    gemm128<<<dim3(32, 32), 256, 0, stream>>>(xn, DIM, W_in, 4096, xz, 4096,
                                              nullptr, 0, DIM);
    // 3. depthwise causal conv + bias + SiLU -> u
    conv_silu<<<8192, 256, 0, stream>>>(xz, conv_w, conv_b, u);
    // 4. xdbl = u @ W_xproj  [4096,2048]@[2048,96]
    xproj_kernel<<<ROWS, 128, 0, stream>>>(u, W_xp, xdbl);
    // 5. delta = softplus(dt @ W_dt + b_dt)
    dtproj_kernel<<<ROWS, 256, 0, stream>>>(xdbl, W_dt, b_dt, delta);
    // 6. chunked parallel scan + skip(D*u) + gate(silu(z)) -> xz[:, :2048]
    scan_p1<<<dim3(DINNER/256, NC, 2), 256, 0, stream>>>(u, delta, xdbl, A_log, P, Hend);
    scan_p2<<<256, 256, 0, stream>>>(P, Hend);
    scan_p3<<<dim3(DINNER/256, NC, 2), 256, 0, stream>>>(u, delta, xdbl, A_log, Dp, Hend, xz);
    // 7. out = x + y @ W_out   [4096,2048]@[2048,1024]
    gemm128<<<dim3(8, 32), 256, 0, stream>>>(xz, 4096, W_out, DIM, out, DIM,
                                             x, DIM, DINNER);
}

// Round 6
// 323.873 us; speedup vs baseline: 6.1914x; 3.1700x over previous
//
#include <hip/hip_runtime.h>
#include <hip/hip_bf16.h>

// B=2, L=2048, DIM=1024, D_INNER=2048, DT_RANK=64, D_STATE=16, D_CONV=4
// ws layout (float offsets), total 31,260,672 floats = 125.0 MB (no live overlaps):
//   region0 @0 (4,194,304): phase A: xnb bf16[4096][1024] @0 (2,097,152 fl),
//                                    W_inT bf16[4096][1024] @2097152 (2,097,152 fl)
//                           phase B (after GEMM1): P fp32 @0, Hend fp32 @2097152
//   xzb   @  4194304: bf16 [4096][4096] (8,388,608 fl)   -> 12582912
//   ubf   @ 12582912: bf16 [4096][2048] (4,194,304 fl)   -> 16777216
//   xdbl  @ 16777216: fp32 [4096][128]  (524,288 fl)     -> 17301504  (dt|B|C|pad)
//   delta @ 17301504: fp32 [4096][2048] (8,388,608 fl)   -> 25690112
//   W_xpT @ 25690112: bf16 [128][2048]  (131,072 fl)     -> 25821184
//   W_dtT @ 25821184: bf16 [2048][64]   (65,536 fl)      -> 25886720
//   dtb   @ 25886720: bf16 [4096][64]   (131,072 fl)     -> 26017792
//   ybf   @ 26017792: bf16 [4096][2048] (4,194,304 fl)   -> 30212096
//   W_outT@ 30212096: bf16 [1024][2048] (1,048,576 fl)   -> 31260672

#define ROWS 4096
#define DIM 1024
#define DINNER 2048
#define LSEQ 2048
#define NC 32
#define CL 64

typedef short short8_t __attribute__((ext_vector_type(8)));
typedef float f32x4_t __attribute__((ext_vector_type(4)));

__device__ __forceinline__ unsigned short f2bf(float f) {
    union { float f; unsigned u; } v; v.f = f;
    unsigned r = v.u + 0x7fffu + ((v.u >> 16) & 1u);
    return (unsigned short)(r >> 16);
}
__device__ __forceinline__ float bf2f(unsigned short b) {
    union { unsigned u; float f; } v; v.u = ((unsigned)b) << 16;
    return v.f;
}

__global__ __launch_bounds__(256) void ln_kernel(const float* __restrict__ x,
    const float* __restrict__ gamma, const float* __restrict__ beta,
    unsigned short* __restrict__ xnb)
{
    const int row = blockIdx.x;
    const int tid = threadIdx.x;
    float4 v = ((const float4*)(x + (long)row * DIM))[tid];
    float s  = v.x + v.y + v.z + v.w;
    float sq = v.x*v.x + v.y*v.y + v.z*v.z + v.w*v.w;
    #pragma unroll
    for (int off = 32; off > 0; off >>= 1) {
        s  += __shfl_down(s,  off, 64);
        sq += __shfl_down(sq, off, 64);
    }
    __shared__ float ss[8], ssq[8];
    const int wid = tid >> 6, lane = tid & 63;
    if (lane == 0) { ss[wid] = s; ssq[wid] = sq; }
    __syncthreads();
    if (tid == 0) {
        float S = 0.f, SQ = 0.f;
        for (int w = 0; w < 4; ++w) { S += ss[w]; SQ += ssq[w]; }
        float mu  = S / (float)DIM;
        float var = SQ / (float)DIM - mu * mu;
        ss[4]  = mu;
        ssq[4] = rsqrtf(var + 1e-5f);
    }
    __syncthreads();
    const float mu = ss[4], rs = ssq[4];
    float4 g = ((const float4*)gamma)[tid];
    float4 b = ((const float4*)beta)[tid];
    ushort4 o;
    o.x = f2bf((v.x - mu) * rs * g.x + b.x);
    o.y = f2bf((v.y - mu) * rs * g.y + b.y);
    o.z = f2bf((v.z - mu) * rs * g.z + b.z);
    o.w = f2bf((v.w - mu) * rs * g.w + b.w);
    *(ushort4*)(xnb + (long)row * DIM + tid * 4) = o;
}

// out[Cpad][R] (bf16) = transpose(in[R][C] fp32); zero for c >= C. 32x32 tiles.
__global__ __launch_bounds__(256) void transpose_bf16(
    const float* __restrict__ in, unsigned short* __restrict__ out,
    int R, int C)
{
    __shared__ float tile[32][33];
    const int c0 = blockIdx.x * 32;
    const int r0 = blockIdx.y * 32;
    const int tx = threadIdx.x & 31, ty = threadIdx.x >> 5;
    #pragma unroll
    for (int i = 0; i < 4; ++i) {
        int r = r0 + ty + i * 8;
        int c = c0 + tx;
        tile[ty + i * 8][tx] = (c < C) ? in[(long)r * C + c] : 0.f;
    }
    __syncthreads();
    #pragma unroll
    for (int i = 0; i < 4; ++i) {
        int c = c0 + ty + i * 8;
        int r = r0 + tx;
        out[(long)c * R + r] = f2bf(tile[tx][ty + i * 8]);
    }
}

// C[M,N] = A[M,K] @ Bt[N,K]^T. bf16 inputs. 128x128 tile, BK=32, 4 waves.
// MODE 0: C=acc. MODE 1: C=acc+aux[row*N+col]. MODE 2: C=softplus(acc+aux[col]).
// OUTBF: 1 -> C is bf16 (ushort*), else fp32.
template <int MODE, int OUTBF>
__global__ __launch_bounds__(256) void gemm_bf16(
    const unsigned short* __restrict__ A,
    const unsigned short* __restrict__ Bt,
    void* __restrict__ Cv,
    const float* __restrict__ aux,
    int M, int N, int K)
{
    __shared__ __align__(16) unsigned short As[128 * 32];
    __shared__ __align__(16) unsigned short Bs[128 * 32];
    const int tid  = threadIdx.x;
    const int wave = tid >> 6, lane = tid & 63;
    const int wr = wave >> 1, wc = wave & 1;
    const int l15 = lane & 15, l4 = lane >> 4;
    const long row0 = (long)blockIdx.y * 128;
    const long col0 = (long)blockIdx.x * 128;

    f32x4_t acc[4][4];
    #pragma unroll
    for (int m = 0; m < 4; ++m)
        #pragma unroll
        for (int n = 0; n < 4; ++n)
            acc[m][n] = (f32x4_t){0.f, 0.f, 0.f, 0.f};

    const int srow = tid >> 2;
    const int scol = (tid & 3) * 8;
    const unsigned short* Ag = A  + (row0 + srow) * (long)K + scol;
    const unsigned short* Bg = Bt + (col0 + srow) * (long)K + scol;
    unsigned short* AsW = As + wave * 512;   // HW appends lane*16B
    unsigned short* BsW = Bs + wave * 512;

    for (int k0 = 0; k0 < K; k0 += 32) {
        __syncthreads();
        __builtin_amdgcn_global_load_lds(
            (const __attribute__((address_space(1))) void*)(Ag + k0),
            (__attribute__((address_space(3))) void*)AsW, 16, 0, 0);
        __builtin_amdgcn_global_load_lds(
            (const __attribute__((address_space(1))) void*)(Ag + 64 * (long)K + k0),
            (__attribute__((address_space(3))) void*)(AsW + 2048), 16, 0, 0);
        __builtin_amdgcn_global_load_lds(
            (const __attribute__((address_space(1))) void*)(Bg + k0),
            (__attribute__((address_space(3))) void*)BsW, 16, 0, 0);
        __builtin_amdgcn_global_load_lds(
            (const __attribute__((address_space(1))) void*)(Bg + 64 * (long)K + k0),
            (__attribute__((address_space(3))) void*)(BsW + 2048), 16, 0, 0);
        __syncthreads();
        short8_t af[4], bf[4];
        #pragma unroll
        for (int m = 0; m < 4; ++m)
            af[m] = *(const short8_t*)&As[(wr * 64 + m * 16 + l15) * 32 + l4 * 8];
        #pragma unroll
        for (int n = 0; n < 4; ++n)
            bf[n] = *(const short8_t*)&Bs[(wc * 64 + n * 16 + l15) * 32 + l4 * 8];
        #pragma unroll
        for (int m = 0; m < 4; ++m)
            #pragma unroll
            for (int n = 0; n < 4; ++n)
                acc[m][n] = __builtin_amdgcn_mfma_f32_16x16x32_bf16(
                    af[m], bf[n], acc[m][n], 0, 0, 0);
    }
    #pragma unroll
    for (int m = 0; m < 4; ++m) {
        #pragma unroll
        for (int n = 0; n < 4; ++n) {
            #pragma unroll
            for (int r = 0; r < 4; ++r) {
                long row = row0 + wr * 64 + m * 16 + l4 * 4 + r;
                long col = col0 + wc * 64 + n * 16 + l15;
                float v = acc[m][n][r];
                if (MODE == 1) v += aux[row * (long)N + col];
                if (MODE == 2) {
                    v += aux[col];
                    v = (v > 20.f) ? v : log1pf(__expf(v));
                }
                if (OUTBF) ((unsigned short*)Cv)[row * (long)N + col] = f2bf(v);
                else       ((float*)Cv)[row * (long)N + col] = v;
            }
        }
    }
}

// u = silu(depthwise causal conv(xzb[:, :2048]) + cb) -> bf16
__global__ __launch_bounds__(256) void conv_silu(
    const unsigned short* __restrict__ xzb, const float* __restrict__ cw,
    const float* __restrict__ cb, unsigned short* __restrict__ ubf)
{
    const int t = blockIdx.x * 256 + threadIdx.x;
    const int dq = t & 511;
    const int l  = (t >> 9) & 2047;
    const int b  = t >> 20;
    const int d  = dq * 4;
    const float4* w4 = (const float4*)(cw + (long)d * 4);
    float4 w0 = w4[0], w1 = w4[1], w2 = w4[2], w3 = w4[3];
    const float* wr[4] = { (const float*)&w0, (const float*)&w1,
                           (const float*)&w2, (const float*)&w3 };
    float4 bias = *(const float4*)(cb + d);
    float acc0 = bias.x, acc1 = bias.y, acc2 = bias.z, acc3 = bias.w;
    const unsigned short* base = xzb + ((long)b * LSEQ) * 4096 + d;
    #pragma unroll
    for (int k = 0; k < 4; ++k) {
        int ls = l - 3 + k;
        if (ls >= 0) {
            ushort4 tv = *(const ushort4*)(base + (long)ls * 4096);
            acc0 = fmaf(wr[0][k], bf2f(tv.x), acc0);
            acc1 = fmaf(wr[1][k], bf2f(tv.y), acc1);
            acc2 = fmaf(wr[2][k], bf2f(tv.z), acc2);
            acc3 = fmaf(wr[3][k], bf2f(tv.w), acc3);
        }
    }
    ushort4 o;
    o.x = f2bf(acc0 / (1.f + __expf(-acc0)));
    o.y = f2bf(acc1 / (1.f + __expf(-acc1)));
    o.z = f2bf(acc2 / (1.f + __expf(-acc2)));
    o.w = f2bf(acc3 / (1.f + __expf(-acc3)));
    *(ushort4*)(ubf + ((long)b * LSEQ + l) * DINNER + d) = o;
}

// dtb[row][k] = bf16(xdbl[row*128 + k]), k < 64
__global__ __launch_bounds__(256) void cvt_dtb(
    const float* __restrict__ xdbl, unsigned short* __restrict__ dtb)
{
    const int i = blockIdx.x * 256 + threadIdx.x;   // 0..65535
    const int r = i >> 4, c4 = (i & 15) * 4;
    float4 v = *(const float4*)(xdbl + (long)r * 128 + c4);
    ushort4 o = { f2bf(v.x), f2bf(v.y), f2bf(v.z), f2bf(v.w) };
    *(ushort4*)(dtb + (long)r * 64 + c4) = o;
}

// Phase 1: per (b, chunk, d): local scan from h=0; write P (cumprod a) and Hend.
__global__ __launch_bounds__(256) void scan_p1(
    const unsigned short* __restrict__ ubf, const float* __restrict__ delta,
    const float* __restrict__ xdbl, const float* __restrict__ A_log,
    float* __restrict__ P, float* __restrict__ Hend)
{
    __shared__ float bsm[CL * 16];
    const int d = blockIdx.x * 256 + threadIdx.x;
    const int c = blockIdx.y;
    const int b = blockIdx.z;
    const long rowbase = (long)b * LSEQ + (long)c * CL;
    for (int i = threadIdx.x; i < CL * 16; i += 256) {
        int t = i >> 4, s = i & 15;
        bsm[i] = xdbl[(rowbase + t) * 128 + 64 + s];
    }
    __syncthreads();
    float A[16];
    #pragma unroll
    for (int s = 0; s < 16; ++s) A[s] = -__expf(A_log[(long)d * 16 + s]);
    float h[16], p[16];
    #pragma unroll
    for (int s = 0; s < 16; ++s) { h[s] = 0.f; p[s] = 1.f; }
    const unsigned short* ub = ubf + rowbase * DINNER + d;
    const float* db = delta + rowbase * DINNER + d;
    for (int t = 0; t < CL; ++t) {
        float dt = db[(long)t * DINNER];
        float du = dt * bf2f(ub[(long)t * DINNER]);
        const float* bv = &bsm[t * 16];
        #pragma unroll
        for (int s = 0; s < 16; ++s) {
            float a = __expf(dt * A[s]);
            p[s] *= a;
            h[s] = fmaf(h[s], a, du * bv[s]);
        }
    }
    const long o = (((long)b * NC + c) * DINNER + d) * 16;
    #pragma unroll
    for (int q = 0; q < 4; ++q) {
        *(float4*)(P    + o + q*4) = make_float4(p[q*4],p[q*4+1],p[q*4+2],p[q*4+3]);
        *(float4*)(Hend + o + q*4) = make_float4(h[q*4],h[q*4+1],h[q*4+2],h[q*4+3]);
    }
}

// Phase 2: sequential over chunks; Hend -> Hin in place.
__global__ __launch_bounds__(256) void scan_p2(
    const float* __restrict__ P, float* __restrict__ H)
{
    const int idx = blockIdx.x * 256 + threadIdx.x;
    const int b = idx >> 15;
    const int rest = idx & 32767;
    float carry = 0.f;
    for (int c = 0; c < NC; ++c) {
        const long a = ((long)(b * NC + c) << 15) + rest;
        float tmp = H[a];
        float pp  = P[a];
        H[a] = carry;
        carry = fmaf(carry, pp, tmp);
    }
}

// Phase 3: re-run local scan from Hin; y + D*u, gate silu(z); write ybf (bf16).
__global__ __launch_bounds__(256) void scan_p3(
    const unsigned short* __restrict__ ubf, const float* __restrict__ delta,
    const float* __restrict__ xdbl, const float* __restrict__ A_log,
    const float* __restrict__ Dp, const float* __restrict__ Hin,
    const unsigned short* __restrict__ xzb, unsigned short* __restrict__ ybf)
{
    __shared__ float bcs[CL * 32];
    const int d = blockIdx.x * 256 + threadIdx.x;
    const int c = blockIdx.y;
    const int b = blockIdx.z;
    const long rowbase = (long)b * LSEQ + (long)c * CL;
    for (int i = threadIdx.x; i < CL * 32; i += 256) {
        int t = i >> 5, s = i & 31;
        bcs[i] = xdbl[(rowbase + t) * 128 + 64 + s];
    }
    __syncthreads();
    float A[16];
    #pragma unroll
    for (int s = 0; s < 16; ++s) A[s] = -__expf(A_log[(long)d * 16 + s]);
    float h[16];
    const long o = (((long)b * NC + c) * DINNER + d) * 16;
    #pragma unroll
    for (int q = 0; q < 4; ++q) {
        float4 hv = *(const float4*)(Hin + o + q*4);
        h[q*4] = hv.x; h[q*4+1] = hv.y; h[q*4+2] = hv.z; h[q*4+3] = hv.w;
    }
    const float Dd = Dp[d];
    const unsigned short* ub = ubf + rowbase * DINNER + d;
    const float* db = delta + rowbase * DINNER + d;
    const unsigned short* zz = xzb + rowbase * 4096 + 2048 + d;
    for (int t = 0; t < CL; ++t) {
        float dt = db[(long)t * DINNER];
        float ut = bf2f(ub[(long)t * DINNER]);
        float zt = bf2f(zz[(long)t * 4096]);
        float du = dt * ut;
        const float* bv = &bcs[t * 32];
        float y = 0.f;
        #pragma unroll
        for (int s = 0; s < 16; ++s) {
            float a = __expf(dt * A[s]);
            h[s] = fmaf(h[s], a, du * bv[s]);
            y = fmaf(h[s], bv[16 + s], y);
        }
        y = fmaf(ut, Dd, y);
        float sig = 1.f / (1.f + __expf(-zt));
        ybf[(rowbase + t) * DINNER + d] = f2bf(y * (zt * sig));
    }
}

extern "C" void kernel_launch(void* const* d_in, const int* in_sizes, int n_in,
                              void* d_out, int out_size, void* d_ws, size_t ws_size,
                              hipStream_t stream) {
    const float* x      = (const float*)d_in[0];
    const float* gamma  = (const float*)d_in[1];
    const float* beta   = (const float*)d_in[2];
    const float* W_in   = (const float*)d_in[3];
    const float* conv_w = (const float*)d_in[4];
    const float* conv_b = (const float*)d_in[5];
    const float* W_xp   = (const float*)d_in[6];
    const float* W_dt   = (const float*)d_in[7];
    const float* b_dt   = (const float*)d_in[8];
    const float* A_log  = (const float*)d_in[9];
    const float* Dp     = (const float*)d_in[10];
    const float* W_out  = (const float*)d_in[11];
    float* out = (float*)d_out;
    float* ws  = (float*)d_ws;

    unsigned short* xnb   = (unsigned short*)ws;                  // phase A
    unsigned short* W_inT = (unsigned short*)(ws + 2097152L);
    float* P              = ws;                                   // phase B
    float* Hend           = ws + 2097152L;
    unsigned short* xzb   = (unsigned short*)(ws + 4194304L);
    unsigned short* ubf   = (unsigned short*)(ws + 12582912L);
    float* xdbl  = ws + 16777216L;
    float* delta = ws + 17301504L;
    unsigned short* W_xpT = (unsigned short*)(ws + 25690112L);
    unsigned short* W_dtT = (unsigned short*)(ws + 25821184L);
    unsigned short* dtb   = (unsigned short*)(ws + 25886720L);
    unsigned short* ybf   = (unsigned short*)(ws + 26017792L);
    unsigned short* W_outT= (unsigned short*)(ws + 30212096L);

    // 1. LayerNorm -> bf16
    ln_kernel<<<ROWS, 256, 0, stream>>>(x, gamma, beta, xnb);
    // weight transposes -> bf16 [N][K]
    transpose_bf16<<<dim3(128, 32), 256, 0, stream>>>(W_in, W_inT, 1024, 4096);
    transpose_bf16<<<dim3(4, 64),  256, 0, stream>>>(W_xp, W_xpT, 2048, 96);
    transpose_bf16<<<dim3(64, 2),  256, 0, stream>>>(W_dt, W_dtT, 64, 2048);
    transpose_bf16<<<dim3(32, 64), 256, 0, stream>>>(W_out, W_outT, 2048, 1024);
    // 2. xz = xn @ W_in   (M=4096, N=4096, K=1024) -> bf16
    gemm_bf16<0,1><<<dim3(32, 32), 256, 0, stream>>>(xnb, W_inT, xzb, nullptr, 4096, 4096, 1024);
    // 3. conv + silu -> ubf
    conv_silu<<<8192, 256, 0, stream>>>(xzb, conv_w, conv_b, ubf);
    // 4. xdbl = u @ W_xproj (padded N=128)
    gemm_bf16<0,0><<<dim3(1, 32), 256, 0, stream>>>(ubf, W_xpT, xdbl, nullptr, 4096, 128, 2048);
    // 5. delta = softplus(dt @ W_dt + b_dt)  (M=4096, N=2048, K=64)
    cvt_dtb<<<256, 256, 0, stream>>>(xdbl, dtb);
    gemm_bf16<2,0><<<dim3(16, 32), 256, 0, stream>>>(dtb, W_dtT, delta, b_dt, 4096, 2048, 64);
    // 6. chunked parallel scan
    scan_p1<<<dim3(DINNER/256, NC, 2), 256, 0, stream>>>(ubf, delta, xdbl, A_log, P, Hend);
    scan_p2<<<256, 256, 0, stream>>>(P, Hend);
    scan_p3<<<dim3(DINNER/256, NC, 2), 256, 0, stream>>>(ubf, delta, xdbl, A_log, Dp, Hend, xzb, ybf);
    // 7. out = x + y @ W_out  (M=4096, N=1024, K=2048)
    gemm_bf16<1,0><<<dim3(8, 32), 256, 0, stream>>>(ybf, W_outT, out, x, 4096, 1024, 2048);
}

// Round 7
// 289.258 us; speedup vs baseline: 6.9323x; 1.1197x over previous
//
#include <hip/hip_runtime.h>
#include <hip/hip_bf16.h>

// B=2, L=2048, DIM=1024, D_INNER=2048, DT_RANK=64, D_STATE=16, D_CONV=4
// ws layout (float offsets), total 35,454,976 floats = 141.8 MB (no live overlaps):
//   region0 @0 (4,194,304): phase A: xnb bf16[4096][1024] @0, W_inT bf16[4096][1024] @2097152
//                           phase B (after GEMM-in): P fp32 @0, Hend fp32 @2097152
//   xzb   @  4194304: bf16 [4096][4096] (8,388,608 fl)   -> 12582912
//   ubf   @ 12582912: bf16 [4096][2048] (4,194,304 fl)   -> 16777216
//   xdbl  @ 16777216: fp32 [4096][128]  (524,288 fl)     -> 17301504  (dt|B|C|pad)
//   delta @ 17301504: fp32 [4096][2048] (8,388,608 fl)   -> 25690112
//   W_xpT @ 25690112: bf16 [128][2048]  (131,072 fl)     -> 25821184
//   W_dtT @ 25821184: bf16 [2048][64]   (65,536 fl)      -> 25886720
//   dtb   @ 25886720: bf16 [4096][64]   (131,072 fl)     -> 26017792
//   ybf   @ 26017792: bf16 [4096][2048] (4,194,304 fl)   -> 30212096
//   W_outT@ 30212096: bf16 [1024][2048] (1,048,576 fl)   -> 31260672
//   part  @ 31260672: fp32 [8][4096][128] (4,194,304 fl) -> 35454976

#define ROWS 4096
#define DIM 1024
#define DINNER 2048
#define LSEQ 2048
#define NC 32
#define CL 64

typedef short short8_t __attribute__((ext_vector_type(8)));
typedef float f32x4_t __attribute__((ext_vector_type(4)));

__device__ __forceinline__ unsigned short f2bf(float f) {
    union { float f; unsigned u; } v; v.f = f;
    unsigned r = v.u + 0x7fffu + ((v.u >> 16) & 1u);
    return (unsigned short)(r >> 16);
}
__device__ __forceinline__ float bf2f(unsigned short b) {
    union { unsigned u; float f; } v; v.u = ((unsigned)b) << 16;
    return v.f;
}

__global__ __launch_bounds__(256) void ln_kernel(const float* __restrict__ x,
    const float* __restrict__ gamma, const float* __restrict__ beta,
    unsigned short* __restrict__ xnb)
{
    const int row = blockIdx.x;
    const int tid = threadIdx.x;
    float4 v = ((const float4*)(x + (long)row * DIM))[tid];
    float s  = v.x + v.y + v.z + v.w;
    float sq = v.x*v.x + v.y*v.y + v.z*v.z + v.w*v.w;
    #pragma unroll
    for (int off = 32; off > 0; off >>= 1) {
        s  += __shfl_down(s,  off, 64);
        sq += __shfl_down(sq, off, 64);
    }
    __shared__ float ss[8], ssq[8];
    const int wid = tid >> 6, lane = tid & 63;
    if (lane == 0) { ss[wid] = s; ssq[wid] = sq; }
    __syncthreads();
    if (tid == 0) {
        float S = 0.f, SQ = 0.f;
        for (int w = 0; w < 4; ++w) { S += ss[w]; SQ += ssq[w]; }
        float mu  = S / (float)DIM;
        float var = SQ / (float)DIM - mu * mu;
        ss[4]  = mu;
        ssq[4] = rsqrtf(var + 1e-5f);
    }
    __syncthreads();
    const float mu = ss[4], rs = ssq[4];
    float4 g = ((const float4*)gamma)[tid];
    float4 b = ((const float4*)beta)[tid];
    ushort4 o;
    o.x = f2bf((v.x - mu) * rs * g.x + b.x);
    o.y = f2bf((v.y - mu) * rs * g.y + b.y);
    o.z = f2bf((v.z - mu) * rs * g.z + b.z);
    o.w = f2bf((v.w - mu) * rs * g.w + b.w);
    *(ushort4*)(xnb + (long)row * DIM + tid * 4) = o;
}

// All four weight transposes in one launch. out[Cpad][R] bf16 = in[R][C]^T, zero-pad c>=C.
__global__ __launch_bounds__(256) void transpose_all(
    const float* __restrict__ W_in,  unsigned short* __restrict__ W_inT,
    const float* __restrict__ W_xp,  unsigned short* __restrict__ W_xpT,
    const float* __restrict__ W_dt,  unsigned short* __restrict__ W_dtT,
    const float* __restrict__ W_out, unsigned short* __restrict__ W_outT)
{
    __shared__ float tile[32][33];
    const int b = blockIdx.x;
    const float* in; unsigned short* out; int R, C, tx, ty;
    if (b < 4096)      { in = W_in;  out = W_inT;  R = 1024; C = 4096; int t = b;        tx = t & 127; ty = t >> 7; }
    else if (b < 4352) { in = W_xp;  out = W_xpT;  R = 2048; C = 96;   int t = b - 4096; tx = t & 3;   ty = t >> 2; }
    else if (b < 4480) { in = W_dt;  out = W_dtT;  R = 64;   C = 2048; int t = b - 4352; tx = t & 63;  ty = t >> 6; }
    else               { in = W_out; out = W_outT; R = 2048; C = 1024; int t = b - 4480; tx = t & 31;  ty = t >> 5; }
    const int c0 = tx * 32, r0 = ty * 32;
    const int lx = threadIdx.x & 31, ly = threadIdx.x >> 5;
    #pragma unroll
    for (int i = 0; i < 4; ++i) {
        int r = r0 + ly + i * 8;
        int c = c0 + lx;
        tile[ly + i * 8][lx] = (c < C) ? in[(long)r * C + c] : 0.f;
    }
    __syncthreads();
    #pragma unroll
    for (int i = 0; i < 4; ++i) {
        int c = c0 + ly + i * 8;
        int r = r0 + lx;
        out[(long)c * R + r] = f2bf(tile[lx][ly + i * 8]);
    }
}

// C[M,N] = A[M,K] @ Bt[N,K]^T. bf16 in, 128x128 tile, BK=32, 4 waves, 2-phase dbuf.
// MODE 0: C=acc (fp32/bf16 per OUTBF). MODE 1: C=acc+aux[row*N+col].
// MODE 2: C=softplus(acc+aux[col]). MODE 3: split-K partials (grid.z slices, fp32).
template <int MODE, int OUTBF>
__global__ __launch_bounds__(256) void gemm_bf16(
    const unsigned short* __restrict__ A,
    const unsigned short* __restrict__ Bt,
    void* __restrict__ Cv,
    const float* __restrict__ aux,
    int M, int N, int K)
{
    __shared__ __align__(16) unsigned short As[2][128 * 32];
    __shared__ __align__(16) unsigned short Bs[2][128 * 32];
    const int tid  = threadIdx.x;
    const int wave = tid >> 6, lane = tid & 63;
    const int wr = wave >> 1, wc = wave & 1;
    const int l15 = lane & 15, l4 = lane >> 4;
    const long row0 = (long)blockIdx.y * 128;
    const long col0 = (long)blockIdx.x * 128;
    int Koff = 0, Klen = K;
    if (MODE == 3) { Klen = K >> 3; Koff = blockIdx.z * Klen; }

    f32x4_t acc[4][4];
    #pragma unroll
    for (int m = 0; m < 4; ++m)
        #pragma unroll
        for (int n = 0; n < 4; ++n)
            acc[m][n] = (f32x4_t){0.f, 0.f, 0.f, 0.f};

    const int srow = tid >> 2;
    const int scol = (tid & 3) * 8;
    const unsigned short* Ag = A  + (row0 + srow) * (long)K + Koff + scol;
    const unsigned short* Bg = Bt + (col0 + srow) * (long)K + Koff + scol;

    auto stage = [&](int buf, int k0) {
        unsigned short* AsW = &As[buf][wave * 512];
        unsigned short* BsW = &Bs[buf][wave * 512];
        __builtin_amdgcn_global_load_lds(
            (const __attribute__((address_space(1))) void*)(Ag + k0),
            (__attribute__((address_space(3))) void*)AsW, 16, 0, 0);
        __builtin_amdgcn_global_load_lds(
            (const __attribute__((address_space(1))) void*)(Ag + 64 * (long)K + k0),
            (__attribute__((address_space(3))) void*)(AsW + 2048), 16, 0, 0);
        __builtin_amdgcn_global_load_lds(
            (const __attribute__((address_space(1))) void*)(Bg + k0),
            (__attribute__((address_space(3))) void*)BsW, 16, 0, 0);
        __builtin_amdgcn_global_load_lds(
            (const __attribute__((address_space(1))) void*)(Bg + 64 * (long)K + k0),
            (__attribute__((address_space(3))) void*)(BsW + 2048), 16, 0, 0);
    };
    auto compute = [&](int buf) {
        short8_t af[4], bf[4];
        #pragma unroll
        for (int m = 0; m < 4; ++m)
            af[m] = *(const short8_t*)&As[buf][(wr * 64 + m * 16 + l15) * 32 + l4 * 8];
        #pragma unroll
        for (int n = 0; n < 4; ++n)
            bf[n] = *(const short8_t*)&Bs[buf][(wc * 64 + n * 16 + l15) * 32 + l4 * 8];
        #pragma unroll
        for (int m = 0; m < 4; ++m)
            #pragma unroll
            for (int n = 0; n < 4; ++n)
                acc[m][n] = __builtin_amdgcn_mfma_f32_16x16x32_bf16(
                    af[m], bf[n], acc[m][n], 0, 0, 0);
    };

    const int nt = Klen >> 5;          // >= 2 for all call sites
    stage(0, 0);
    __syncthreads();                   // prologue tile resident
    int cur = 0;
    for (int t = 0; t < nt - 1; ++t) {
        stage(cur ^ 1, (t + 1) * 32);  // prefetch next tile (in flight during compute)
        compute(cur);
        __syncthreads();               // drain prefetch + all waves done reading cur
        cur ^= 1;
    }
    compute(cur);

    float* Cf = (float*)Cv;
    unsigned short* Cb = (unsigned short*)Cv;
    if (MODE == 3) Cf += (long)blockIdx.z * M * (long)N;
    #pragma unroll
    for (int m = 0; m < 4; ++m) {
        #pragma unroll
        for (int n = 0; n < 4; ++n) {
            #pragma unroll
            for (int r = 0; r < 4; ++r) {
                long row = row0 + wr * 64 + m * 16 + l4 * 4 + r;
                long col = col0 + wc * 64 + n * 16 + l15;
                float v = acc[m][n][r];
                if (MODE == 1) v += aux[row * (long)N + col];
                if (MODE == 2) {
                    v += aux[col];
                    v = (v > 20.f) ? v : log1pf(__expf(v));
                }
                if (OUTBF) Cb[row * (long)N + col] = f2bf(v);
                else       Cf[row * (long)N + col] = v;
            }
        }
    }
}

// xdbl = sum over 8 split-K partials; also emit dtb = bf16(dt cols 0:64).
__global__ __launch_bounds__(256) void reduce_xdbl(
    const float* __restrict__ part, float* __restrict__ xdbl,
    unsigned short* __restrict__ dtb)
{
    const int i = blockIdx.x * 256 + threadIdx.x;   // 0..131071 (float4 units)
    const int r = i >> 5, c4 = (i & 31) * 4;
    float4 s = {0.f, 0.f, 0.f, 0.f};
    #pragma unroll
    for (int k = 0; k < 8; ++k) {
        float4 v = *(const float4*)(part + (long)k * 524288 + (long)r * 128 + c4);
        s.x += v.x; s.y += v.y; s.z += v.z; s.w += v.w;
    }
    *(float4*)(xdbl + (long)r * 128 + c4) = s;
    if (c4 < 64) {
        ushort4 o = { f2bf(s.x), f2bf(s.y), f2bf(s.z), f2bf(s.w) };
        *(ushort4*)(dtb + (long)r * 64 + c4) = o;
    }
}

// u = silu(depthwise causal conv(xzb[:, :2048]) + cb) -> bf16
__global__ __launch_bounds__(256) void conv_silu(
    const unsigned short* __restrict__ xzb, const float* __restrict__ cw,
    const float* __restrict__ cb, unsigned short* __restrict__ ubf)
{
    const int t = blockIdx.x * 256 + threadIdx.x;
    const int dq = t & 511;
    const int l  = (t >> 9) & 2047;
    const int b  = t >> 20;
    const int d  = dq * 4;
    const float4* w4 = (const float4*)(cw + (long)d * 4);
    float4 w0 = w4[0], w1 = w4[1], w2 = w4[2], w3 = w4[3];
    const float* wr[4] = { (const float*)&w0, (const float*)&w1,
                           (const float*)&w2, (const float*)&w3 };
    float4 bias = *(const float4*)(cb + d);
    float acc0 = bias.x, acc1 = bias.y, acc2 = bias.z, acc3 = bias.w;
    const unsigned short* base = xzb + ((long)b * LSEQ) * 4096 + d;
    #pragma unroll
    for (int k = 0; k < 4; ++k) {
        int ls = l - 3 + k;
        if (ls >= 0) {
            ushort4 tv = *(const ushort4*)(base + (long)ls * 4096);
            acc0 = fmaf(wr[0][k], bf2f(tv.x), acc0);
            acc1 = fmaf(wr[1][k], bf2f(tv.y), acc1);
            acc2 = fmaf(wr[2][k], bf2f(tv.z), acc2);
            acc3 = fmaf(wr[3][k], bf2f(tv.w), acc3);
        }
    }
    ushort4 o;
    o.x = f2bf(acc0 / (1.f + __expf(-acc0)));
    o.y = f2bf(acc1 / (1.f + __expf(-acc1)));
    o.z = f2bf(acc2 / (1.f + __expf(-acc2)));
    o.w = f2bf(acc3 / (1.f + __expf(-acc3)));
    *(ushort4*)(ubf + ((long)b * LSEQ + l) * DINNER + d) = o;
}

// Phase 1: per (b, chunk, d): local scan from h=0; write P (cumprod a) and Hend.
__global__ __launch_bounds__(256) void scan_p1(
    const unsigned short* __restrict__ ubf, const float* __restrict__ delta,
    const float* __restrict__ xdbl, const float* __restrict__ A_log,
    float* __restrict__ P, float* __restrict__ Hend)
{
    __shared__ float bsm[CL * 16];
    const int d = blockIdx.x * 256 + threadIdx.x;
    const int c = blockIdx.y;
    const int b = blockIdx.z;
    const long rowbase = (long)b * LSEQ + (long)c * CL;
    for (int i = threadIdx.x; i < CL * 16; i += 256) {
        int t = i >> 4, s = i & 15;
        bsm[i] = xdbl[(rowbase + t) * 128 + 64 + s];
    }
    __syncthreads();
    float A[16];
    #pragma unroll
    for (int s = 0; s < 16; ++s) A[s] = -__expf(A_log[(long)d * 16 + s]);
    float h[16], p[16];
    #pragma unroll
    for (int s = 0; s < 16; ++s) { h[s] = 0.f; p[s] = 1.f; }
    const unsigned short* ub = ubf + rowbase * DINNER + d;
    const float* db = delta + rowbase * DINNER + d;
    for (int t = 0; t < CL; ++t) {
        float dt = db[(long)t * DINNER];
        float du = dt * bf2f(ub[(long)t * DINNER]);
        const float* bv = &bsm[t * 16];
        #pragma unroll
        for (int s = 0; s < 16; ++s) {
            float a = __expf(dt * A[s]);
            p[s] *= a;
            h[s] = fmaf(h[s], a, du * bv[s]);
        }
    }
    const long o = (((long)b * NC + c) * DINNER + d) * 16;
    #pragma unroll
    for (int q = 0; q < 4; ++q) {
        *(float4*)(P    + o + q*4) = make_float4(p[q*4],p[q*4+1],p[q*4+2],p[q*4+3]);
        *(float4*)(Hend + o + q*4) = make_float4(h[q*4],h[q*4+1],h[q*4+2],h[q*4+3]);
    }
}

// Phase 2: sequential over chunks; Hend -> Hin in place.
__global__ __launch_bounds__(256) void scan_p2(
    const float* __restrict__ P, float* __restrict__ H)
{
    const int idx = blockIdx.x * 256 + threadIdx.x;
    const int b = idx >> 15;
    const int rest = idx & 32767;
    float carry = 0.f;
    for (int c = 0; c < NC; ++c) {
        const long a = ((long)(b * NC + c) << 15) + rest;
        float tmp = H[a];
        float pp  = P[a];
        H[a] = carry;
        carry = fmaf(carry, pp, tmp);
    }
}

// Phase 3: re-run local scan from Hin; y + D*u, gate silu(z); write ybf (bf16).
__global__ __launch_bounds__(256) void scan_p3(
    const unsigned short* __restrict__ ubf, const float* __restrict__ delta,
    const float* __restrict__ xdbl, const float* __restrict__ A_log,
    const float* __restrict__ Dp, const float* __restrict__ Hin,
    const unsigned short* __restrict__ xzb, unsigned short* __restrict__ ybf)
{
    __shared__ float bcs[CL * 32];
    const int d = blockIdx.x * 256 + threadIdx.x;
    const int c = blockIdx.y;
    const int b = blockIdx.z;
    const long rowbase = (long)b * LSEQ + (long)c * CL;
    for (int i = threadIdx.x; i < CL * 32; i += 256) {
        int t = i >> 5, s = i & 31;
        bcs[i] = xdbl[(rowbase + t) * 128 + 64 + s];
    }
    __syncthreads();
    float A[16];
    #pragma unroll
    for (int s = 0; s < 16; ++s) A[s] = -__expf(A_log[(long)d * 16 + s]);
    float h[16];
    const long o = (((long)b * NC + c) * DINNER + d) * 16;
    #pragma unroll
    for (int q = 0; q < 4; ++q) {
        float4 hv = *(const float4*)(Hin + o + q*4);
        h[q*4] = hv.x; h[q*4+1] = hv.y; h[q*4+2] = hv.z; h[q*4+3] = hv.w;
    }
    const float Dd = Dp[d];
    const unsigned short* ub = ubf + rowbase * DINNER + d;
    const float* db = delta + rowbase * DINNER + d;
    const unsigned short* zz = xzb + rowbase * 4096 + 2048 + d;
    for (int t = 0; t < CL; ++t) {
        float dt = db[(long)t * DINNER];
        float ut = bf2f(ub[(long)t * DINNER]);
        float zt = bf2f(zz[(long)t * 4096]);
        float du = dt * ut;
        const float* bv = &bcs[t * 32];
        float y = 0.f;
        #pragma unroll
        for (int s = 0; s < 16; ++s) {
            float a = __expf(dt * A[s]);
            h[s] = fmaf(h[s], a, du * bv[s]);
            y = fmaf(h[s], bv[16 + s], y);
        }
        y = fmaf(ut, Dd, y);
        float sig = 1.f / (1.f + __expf(-zt));
        ybf[(rowbase + t) * DINNER + d] = f2bf(y * (zt * sig));
    }
}

extern "C" void kernel_launch(void* const* d_in, const int* in_sizes, int n_in,
                              void* d_out, int out_size, void* d_ws, size_t ws_size,
                              hipStream_t stream) {
    const float* x      = (const float*)d_in[0];
    const float* gamma  = (const float*)d_in[1];
    const float* beta   = (const float*)d_in[2];
    const float* W_in   = (const float*)d_in[3];
    const float* conv_w = (const float*)d_in[4];
    const float* conv_b = (const float*)d_in[5];
    const float* W_xp   = (const float*)d_in[6];
    const float* W_dt   = (const float*)d_in[7];
    const float* b_dt   = (const float*)d_in[8];
    const float* A_log  = (const float*)d_in[9];
    const float* Dp     = (const float*)d_in[10];
    const float* W_out  = (const float*)d_in[11];
    float* out = (float*)d_out;
    float* ws  = (float*)d_ws;

    unsigned short* xnb   = (unsigned short*)ws;                  // phase A
    unsigned short* W_inT = (unsigned short*)(ws + 2097152L);
    float* P              = ws;                                   // phase B
    float* Hend           = ws + 2097152L;
    unsigned short* xzb   = (unsigned short*)(ws + 4194304L);
    unsigned short* ubf   = (unsigned short*)(ws + 12582912L);
    float* xdbl  = ws + 16777216L;
    float* delta = ws + 17301504L;
    unsigned short* W_xpT = (unsigned short*)(ws + 25690112L);
    unsigned short* W_dtT = (unsigned short*)(ws + 25821184L);
    unsigned short* dtb   = (unsigned short*)(ws + 25886720L);
    unsigned short* ybf   = (unsigned short*)(ws + 26017792L);
    unsigned short* W_outT= (unsigned short*)(ws + 30212096L);
    float* part           = ws + 31260672L;

    // 1. LayerNorm -> bf16
    ln_kernel<<<ROWS, 256, 0, stream>>>(x, gamma, beta, xnb);
    // 2. all weight transposes -> bf16 [N][K]
    transpose_all<<<6528, 256, 0, stream>>>(W_in, W_inT, W_xp, W_xpT,
                                            W_dt, W_dtT, W_out, W_outT);
    // 3. xz = xn @ W_in   (M=4096, N=4096, K=1024) -> bf16
    gemm_bf16<0,1><<<dim3(32, 32), 256, 0, stream>>>(xnb, W_inT, xzb, nullptr, 4096, 4096, 1024);
    // 4. conv + silu -> ubf
    conv_silu<<<8192, 256, 0, stream>>>(xzb, conv_w, conv_b, ubf);
    // 5. xdbl = u @ W_xproj: split-K x8 partials + reduce (also emits dtb bf16)
    gemm_bf16<3,0><<<dim3(1, 32, 8), 256, 0, stream>>>(ubf, W_xpT, part, nullptr, 4096, 128, 2048);
    reduce_xdbl<<<512, 256, 0, stream>>>(part, xdbl, dtb);
    // 6. delta = softplus(dt @ W_dt + b_dt)  (M=4096, N=2048, K=64)
    gemm_bf16<2,0><<<dim3(16, 32), 256, 0, stream>>>(dtb, W_dtT, delta, b_dt, 4096, 2048, 64);
    // 7. chunked parallel scan
    scan_p1<<<dim3(DINNER/256, NC, 2), 256, 0, stream>>>(ubf, delta, xdbl, A_log, P, Hend);
    scan_p2<<<256, 256, 0, stream>>>(P, Hend);
    scan_p3<<<dim3(DINNER/256, NC, 2), 256, 0, stream>>>(ubf, delta, xdbl, A_log, Dp, Hend, xzb, ybf);
    // 8. out = x + y @ W_out  (M=4096, N=1024, K=2048)
    gemm_bf16<1,0><<<dim3(8, 32), 256, 0, stream>>>(ybf, W_outT, out, x, 4096, 1024, 2048);
}

// Round 8
// 272.765 us; speedup vs baseline: 7.3514x; 1.0605x over previous
//
#include <hip/hip_runtime.h>
#include <hip/hip_bf16.h>

// B=2, L=2048, DIM=1024, D_INNER=2048, DT_RANK=64, D_STATE=16, D_CONV=4
// ws layout (float offsets), total 35,454,976 floats = 141.8 MB (no live overlaps):
//   region0 @0 (4,194,304): phase A: xnb bf16[4096][1024] @0, W_inT bf16[4096][1024] @2097152
//                           phase B (after GEMM-in): P fp32 @0, Hend fp32 @2097152
//   xzb   @  4194304: bf16 [4096][4096] (8,388,608 fl)   -> 12582912
//   ubf   @ 12582912: bf16 [4096][2048] (4,194,304 fl)   -> 16777216
//   xdbl  @ 16777216: fp32 [4096][128]  (524,288 fl)     -> 17301504  (dt|B|C|pad)
//   delta @ 17301504: bf16 [4096][2048] (region oversized; 2,097,152 fl used)
//   W_xpT @ 25690112: bf16 [128][2048]  (131,072 fl)
//   W_dtT @ 25821184: bf16 [2048][64]   (65,536 fl)
//   dtb   @ 25886720: bf16 [4096][64]   (131,072 fl)
//   ybf   @ 26017792: bf16 [4096][2048] (4,194,304 fl)
//   W_outT@ 30212096: bf16 [1024][2048] (1,048,576 fl)
//   part  @ 31260672: fp32 [8][4096][128] (4,194,304 fl) -> 35454976

#define ROWS 4096
#define DIM 1024
#define DINNER 2048
#define LSEQ 2048
#define NC 32
#define CL 64

typedef short short8_t __attribute__((ext_vector_type(8)));
typedef float f32x4_t __attribute__((ext_vector_type(4)));

__device__ __forceinline__ unsigned short f2bf(float f) {
    union { float f; unsigned u; } v; v.f = f;
    unsigned r = v.u + 0x7fffu + ((v.u >> 16) & 1u);
    return (unsigned short)(r >> 16);
}
__device__ __forceinline__ float bf2f(unsigned short b) {
    union { unsigned u; float f; } v; v.u = ((unsigned)b) << 16;
    return v.f;
}

__global__ __launch_bounds__(256) void ln_kernel(const float* __restrict__ x,
    const float* __restrict__ gamma, const float* __restrict__ beta,
    unsigned short* __restrict__ xnb)
{
    const int row = blockIdx.x;
    const int tid = threadIdx.x;
    float4 v = ((const float4*)(x + (long)row * DIM))[tid];
    float s  = v.x + v.y + v.z + v.w;
    float sq = v.x*v.x + v.y*v.y + v.z*v.z + v.w*v.w;
    #pragma unroll
    for (int off = 32; off > 0; off >>= 1) {
        s  += __shfl_down(s,  off, 64);
        sq += __shfl_down(sq, off, 64);
    }
    __shared__ float ss[8], ssq[8];
    const int wid = tid >> 6, lane = tid & 63;
    if (lane == 0) { ss[wid] = s; ssq[wid] = sq; }
    __syncthreads();
    if (tid == 0) {
        float S = 0.f, SQ = 0.f;
        for (int w = 0; w < 4; ++w) { S += ss[w]; SQ += ssq[w]; }
        float mu  = S / (float)DIM;
        float var = SQ / (float)DIM - mu * mu;
        ss[4]  = mu;
        ssq[4] = rsqrtf(var + 1e-5f);
    }
    __syncthreads();
    const float mu = ss[4], rs = ssq[4];
    float4 g = ((const float4*)gamma)[tid];
    float4 b = ((const float4*)beta)[tid];
    ushort4 o;
    o.x = f2bf((v.x - mu) * rs * g.x + b.x);
    o.y = f2bf((v.y - mu) * rs * g.y + b.y);
    o.z = f2bf((v.z - mu) * rs * g.z + b.z);
    o.w = f2bf((v.w - mu) * rs * g.w + b.w);
    *(ushort4*)(xnb + (long)row * DIM + tid * 4) = o;
}

// All four weight transposes in one launch. out[Cpad][R] bf16 = in[R][C]^T, zero-pad c>=C.
__global__ __launch_bounds__(256) void transpose_all(
    const float* __restrict__ W_in,  unsigned short* __restrict__ W_inT,
    const float* __restrict__ W_xp,  unsigned short* __restrict__ W_xpT,
    const float* __restrict__ W_dt,  unsigned short* __restrict__ W_dtT,
    const float* __restrict__ W_out, unsigned short* __restrict__ W_outT)
{
    __shared__ float tile[32][33];
    const int b = blockIdx.x;
    const float* in; unsigned short* out; int R, C, tx, ty;
    if (b < 4096)      { in = W_in;  out = W_inT;  R = 1024; C = 4096; int t = b;        tx = t & 127; ty = t >> 7; }
    else if (b < 4352) { in = W_xp;  out = W_xpT;  R = 2048; C = 96;   int t = b - 4096; tx = t & 3;   ty = t >> 2; }
    else if (b < 4480) { in = W_dt;  out = W_dtT;  R = 64;   C = 2048; int t = b - 4352; tx = t & 63;  ty = t >> 6; }
    else               { in = W_out; out = W_outT; R = 2048; C = 1024; int t = b - 4480; tx = t & 31;  ty = t >> 5; }
    const int c0 = tx * 32, r0 = ty * 32;
    const int lx = threadIdx.x & 31, ly = threadIdx.x >> 5;
    #pragma unroll
    for (int i = 0; i < 4; ++i) {
        int r = r0 + ly + i * 8;
        int c = c0 + lx;
        tile[ly + i * 8][lx] = (c < C) ? in[(long)r * C + c] : 0.f;
    }
    __syncthreads();
    #pragma unroll
    for (int i = 0; i < 4; ++i) {
        int c = c0 + ly + i * 8;
        int r = r0 + lx;
        out[(long)c * R + r] = f2bf(tile[lx][ly + i * 8]);
    }
}

// C[M,N] = A[M,K] @ Bt[N,K]^T. bf16 in. 128x128 tile, BK=32, 4 waves.
// Depth-3 pipeline: counted vmcnt (never 0 mid-loop), raw s_barrier, chunk-XOR LDS swizzle.
// MODE 0: C=acc. MODE 1: C=acc+aux[row*N+col]. MODE 2: C=softplus(acc+aux[col]).
// MODE 3: split-K partials (grid.z = 8 slices, fp32). OUTBF: 1 -> bf16 out.
template <int MODE, int OUTBF>
__global__ __launch_bounds__(256) void gemm_bf16(
    const unsigned short* __restrict__ A,
    const unsigned short* __restrict__ Bt,
    void* __restrict__ Cv,
    const float* __restrict__ aux,
    int M, int N, int K)
{
    __shared__ __align__(16) unsigned short As[3][128 * 32];
    __shared__ __align__(16) unsigned short Bs[3][128 * 32];
    const int tid  = threadIdx.x;
    const int wave = tid >> 6, lane = tid & 63;
    const int wr = wave >> 1, wc = wave & 1;
    const int l15 = lane & 15, l4 = lane >> 4;
    const long row0 = (long)blockIdx.y * 128;
    const long col0 = (long)blockIdx.x * 128;
    int Koff = 0, Klen = K;
    if (MODE == 3) { Klen = K >> 3; Koff = blockIdx.z * Klen; }

    f32x4_t acc[4][4];
    #pragma unroll
    for (int m = 0; m < 4; ++m)
        #pragma unroll
        for (int n = 0; n < 4; ++n)
            acc[m][n] = (f32x4_t){0.f, 0.f, 0.f, 0.f};

    // Staging: thread t stages row srow = t>>2, 16B chunk (t&3), with the global
    // SOURCE chunk XOR-swizzled by (srow&3). LDS dest stays linear (gload_lds
    // requirement); the read applies the same XOR -> logical layout restored,
    // banks spread 8-way -> ~2 lanes/bank (free).
    const int srow = tid >> 2;
    const int scol = ((tid & 3) ^ (srow & 3)) * 8;
    const unsigned short* Ag = A  + (row0 + srow) * (long)K + Koff + scol;
    const unsigned short* Bg = Bt + (col0 + srow) * (long)K + Koff + scol;

    auto stage = [&](int buf, int k0) {
        unsigned short* AsW = &As[buf][wave * 512];
        unsigned short* BsW = &Bs[buf][wave * 512];
        __builtin_amdgcn_global_load_lds(
            (const __attribute__((address_space(1))) void*)(Ag + k0),
            (__attribute__((address_space(3))) void*)AsW, 16, 0, 0);
        __builtin_amdgcn_global_load_lds(
            (const __attribute__((address_space(1))) void*)(Ag + 64 * (long)K + k0),
            (__attribute__((address_space(3))) void*)(AsW + 2048), 16, 0, 0);
        __builtin_amdgcn_global_load_lds(
            (const __attribute__((address_space(1))) void*)(Bg + k0),
            (__attribute__((address_space(3))) void*)BsW, 16, 0, 0);
        __builtin_amdgcn_global_load_lds(
            (const __attribute__((address_space(1))) void*)(Bg + 64 * (long)K + k0),
            (__attribute__((address_space(3))) void*)(BsW + 2048), 16, 0, 0);
    };
    const int rchunk = (l4 ^ (l15 & 3)) * 8;   // swizzled read chunk (ushorts)
    auto compute = [&](int buf) {
        const unsigned short* Ab = As[buf];
        const unsigned short* Bb = Bs[buf];
        short8_t af[4], bf[4];
        #pragma unroll
        for (int m = 0; m < 4; ++m)
            af[m] = *(const short8_t*)&Ab[(wr * 64 + m * 16 + l15) * 32 + rchunk];
        #pragma unroll
        for (int n = 0; n < 4; ++n)
            bf[n] = *(const short8_t*)&Bb[(wc * 64 + n * 16 + l15) * 32 + rchunk];
        __builtin_amdgcn_s_setprio(1);
        #pragma unroll
        for (int m = 0; m < 4; ++m)
            #pragma unroll
            for (int n = 0; n < 4; ++n)
                acc[m][n] = __builtin_amdgcn_mfma_f32_16x16x32_bf16(
                    af[m], bf[n], acc[m][n], 0, 0, 0);
        __builtin_amdgcn_s_setprio(0);
    };

    const int nt = Klen >> 5;           // >= 2 at every call site
    stage(0, 0);
    if (nt > 1) stage(1, 32);
    if (nt > 2) stage(2, 64);
    int cur = 0;
    for (int t = 0; t < nt; ++t) {
        // Per-wave: 4 loads per stage. Wait so tile t's 4 loads are complete,
        // leaving future tiles' loads in flight (counted vmcnt - T4).
        if (t + 2 < nt)      asm volatile("s_waitcnt vmcnt(8)" ::: "memory");
        else if (t + 1 < nt) asm volatile("s_waitcnt vmcnt(4)" ::: "memory");
        else                 asm volatile("s_waitcnt vmcnt(0)" ::: "memory");
        __builtin_amdgcn_s_barrier();           // all waves' tile-t slices resident
        __builtin_amdgcn_sched_barrier(0);      // no ds_read hoist above barrier
        compute(cur);
        __builtin_amdgcn_s_barrier();           // all waves done reading buf[cur]
        if (t + 3 < nt) stage(cur, (t + 3) * 32);
        cur = (cur == 2) ? 0 : cur + 1;
    }

    float* Cf = (float*)Cv;
    unsigned short* Cb = (unsigned short*)Cv;
    if (MODE == 3) Cf += (long)blockIdx.z * M * (long)N;
    #pragma unroll
    for (int m = 0; m < 4; ++m) {
        #pragma unroll
        for (int n = 0; n < 4; ++n) {
            #pragma unroll
            for (int r = 0; r < 4; ++r) {
                long row = row0 + wr * 64 + m * 16 + l4 * 4 + r;
                long col = col0 + wc * 64 + n * 16 + l15;
                float v = acc[m][n][r];
                if (MODE == 1) v += aux[row * (long)N + col];
                if (MODE == 2) {
                    v += aux[col];
                    v = (v > 20.f) ? v : log1pf(__expf(v));
                }
                if (OUTBF) Cb[row * (long)N + col] = f2bf(v);
                else       Cf[row * (long)N + col] = v;
            }
        }
    }
}

// xdbl = sum over 8 split-K partials; also emit dtb = bf16(dt cols 0:64).
__global__ __launch_bounds__(256) void reduce_xdbl(
    const float* __restrict__ part, float* __restrict__ xdbl,
    unsigned short* __restrict__ dtb)
{
    const int i = blockIdx.x * 256 + threadIdx.x;   // 0..131071 (float4 units)
    const int r = i >> 5, c4 = (i & 31) * 4;
    float4 s = {0.f, 0.f, 0.f, 0.f};
    #pragma unroll
    for (int k = 0; k < 8; ++k) {
        float4 v = *(const float4*)(part + (long)k * 524288 + (long)r * 128 + c4);
        s.x += v.x; s.y += v.y; s.z += v.z; s.w += v.w;
    }
    *(float4*)(xdbl + (long)r * 128 + c4) = s;
    if (c4 < 64) {
        ushort4 o = { f2bf(s.x), f2bf(s.y), f2bf(s.z), f2bf(s.w) };
        *(ushort4*)(dtb + (long)r * 64 + c4) = o;
    }
}

// u = silu(depthwise causal conv(xzb[:, :2048]) + cb) -> bf16
__global__ __launch_bounds__(256) void conv_silu(
    const unsigned short* __restrict__ xzb, const float* __restrict__ cw,
    const float* __restrict__ cb, unsigned short* __restrict__ ubf)
{
    const int t = blockIdx.x * 256 + threadIdx.x;
    const int dq = t & 511;
    const int l  = (t >> 9) & 2047;
    const int b  = t >> 20;
    const int d  = dq * 4;
    const float4* w4 = (const float4*)(cw + (long)d * 4);
    float4 w0 = w4[0], w1 = w4[1], w2 = w4[2], w3 = w4[3];
    const float* wr[4] = { (const float*)&w0, (const float*)&w1,
                           (const float*)&w2, (const float*)&w3 };
    float4 bias = *(const float4*)(cb + d);
    float acc0 = bias.x, acc1 = bias.y, acc2 = bias.z, acc3 = bias.w;
    const unsigned short* base = xzb + ((long)b * LSEQ) * 4096 + d;
    #pragma unroll
    for (int k = 0; k < 4; ++k) {
        int ls = l - 3 + k;
        if (ls >= 0) {
            ushort4 tv = *(const ushort4*)(base + (long)ls * 4096);
            acc0 = fmaf(wr[0][k], bf2f(tv.x), acc0);
            acc1 = fmaf(wr[1][k], bf2f(tv.y), acc1);
            acc2 = fmaf(wr[2][k], bf2f(tv.z), acc2);
            acc3 = fmaf(wr[3][k], bf2f(tv.w), acc3);
        }
    }
    ushort4 o;
    o.x = f2bf(acc0 / (1.f + __expf(-acc0)));
    o.y = f2bf(acc1 / (1.f + __expf(-acc1)));
    o.z = f2bf(acc2 / (1.f + __expf(-acc2)));
    o.w = f2bf(acc3 / (1.f + __expf(-acc3)));
    *(ushort4*)(ubf + ((long)b * LSEQ + l) * DINNER + d) = o;
}

// Phase 1: per (b, chunk, d): local scan from h=0; write P (cumprod a) and Hend.
__global__ __launch_bounds__(256) void scan_p1(
    const unsigned short* __restrict__ ubf, const unsigned short* __restrict__ delta,
    const float* __restrict__ xdbl, const float* __restrict__ A_log,
    float* __restrict__ P, float* __restrict__ Hend)
{
    __shared__ float bsm[CL * 16];
    const int d = blockIdx.x * 256 + threadIdx.x;
    const int c = blockIdx.y;
    const int b = blockIdx.z;
    const long rowbase = (long)b * LSEQ + (long)c * CL;
    for (int i = threadIdx.x; i < CL * 16; i += 256) {
        int t = i >> 4, s = i & 15;
        bsm[i] = xdbl[(rowbase + t) * 128 + 64 + s];
    }
    __syncthreads();
    float A[16];
    #pragma unroll
    for (int s = 0; s < 16; ++s) A[s] = -__expf(A_log[(long)d * 16 + s]);
    float h[16], p[16];
    #pragma unroll
    for (int s = 0; s < 16; ++s) { h[s] = 0.f; p[s] = 1.f; }
    const unsigned short* ub = ubf + rowbase * DINNER + d;
    const unsigned short* db = delta + rowbase * DINNER + d;
    for (int t = 0; t < CL; ++t) {
        float dt = bf2f(db[(long)t * DINNER]);
        float du = dt * bf2f(ub[(long)t * DINNER]);
        const float* bv = &bsm[t * 16];
        #pragma unroll
        for (int s = 0; s < 16; ++s) {
            float a = __expf(dt * A[s]);
            p[s] *= a;
            h[s] = fmaf(h[s], a, du * bv[s]);
        }
    }
    const long o = (((long)b * NC + c) * DINNER + d) * 16;
    #pragma unroll
    for (int q = 0; q < 4; ++q) {
        *(float4*)(P    + o + q*4) = make_float4(p[q*4],p[q*4+1],p[q*4+2],p[q*4+3]);
        *(float4*)(Hend + o + q*4) = make_float4(h[q*4],h[q*4+1],h[q*4+2],h[q*4+3]);
    }
}

// Phase 2: sequential over chunks; Hend -> Hin in place.
__global__ __launch_bounds__(256) void scan_p2(
    const float* __restrict__ P, float* __restrict__ H)
{
    const int idx = blockIdx.x * 256 + threadIdx.x;
    const int b = idx >> 15;
    const int rest = idx & 32767;
    float carry = 0.f;
    for (int c = 0; c < NC; ++c) {
        const long a = ((long)(b * NC + c) << 15) + rest;
        float tmp = H[a];
        float pp  = P[a];
        H[a] = carry;
        carry = fmaf(carry, pp, tmp);
    }
}

// Phase 3: re-run local scan from Hin; y + D*u, gate silu(z); write ybf (bf16).
__global__ __launch_bounds__(256) void scan_p3(
    const unsigned short* __restrict__ ubf, const unsigned short* __restrict__ delta,
    const float* __restrict__ xdbl, const float* __restrict__ A_log,
    const float* __restrict__ Dp, const float* __restrict__ Hin,
    const unsigned short* __restrict__ xzb, unsigned short* __restrict__ ybf)
{
    __shared__ float bcs[CL * 32];
    const int d = blockIdx.x * 256 + threadIdx.x;
    const int c = blockIdx.y;
    const int b = blockIdx.z;
    const long rowbase = (long)b * LSEQ + (long)c * CL;
    for (int i = threadIdx.x; i < CL * 32; i += 256) {
        int t = i >> 5, s = i & 31;
        bcs[i] = xdbl[(rowbase + t) * 128 + 64 + s];
    }
    __syncthreads();
    float A[16];
    #pragma unroll
    for (int s = 0; s < 16; ++s) A[s] = -__expf(A_log[(long)d * 16 + s]);
    float h[16];
    const long o = (((long)b * NC + c) * DINNER + d) * 16;
    #pragma unroll
    for (int q = 0; q < 4; ++q) {
        float4 hv = *(const float4*)(Hin + o + q*4);
        h[q*4] = hv.x; h[q*4+1] = hv.y; h[q*4+2] = hv.z; h[q*4+3] = hv.w;
    }
    const float Dd = Dp[d];
    const unsigned short* ub = ubf + rowbase * DINNER + d;
    const unsigned short* db = delta + rowbase * DINNER + d;
    const unsigned short* zz = xzb + rowbase * 4096 + 2048 + d;
    for (int t = 0; t < CL; ++t) {
        float dt = bf2f(db[(long)t * DINNER]);
        float ut = bf2f(ub[(long)t * DINNER]);
        float zt = bf2f(zz[(long)t * 4096]);
        float du = dt * ut;
        const float* bv = &bcs[t * 32];
        float y = 0.f;
        #pragma unroll
        for (int s = 0; s < 16; ++s) {
            float a = __expf(dt * A[s]);
            h[s] = fmaf(h[s], a, du * bv[s]);
            y = fmaf(h[s], bv[16 + s], y);
        }
        y = fmaf(ut, Dd, y);
        float sig = 1.f / (1.f + __expf(-zt));
        ybf[(rowbase + t) * DINNER + d] = f2bf(y * (zt * sig));
    }
}

extern "C" void kernel_launch(void* const* d_in, const int* in_sizes, int n_in,
                              void* d_out, int out_size, void* d_ws, size_t ws_size,
                              hipStream_t stream) {
    const float* x      = (const float*)d_in[0];
    const float* gamma  = (const float*)d_in[1];
    const float* beta   = (const float*)d_in[2];
    const float* W_in   = (const float*)d_in[3];
    const float* conv_w = (const float*)d_in[4];
    const float* conv_b = (const float*)d_in[5];
    const float* W_xp   = (const float*)d_in[6];
    const float* W_dt   = (const float*)d_in[7];
    const float* b_dt   = (const float*)d_in[8];
    const float* A_log  = (const float*)d_in[9];
    const float* Dp     = (const float*)d_in[10];
    const float* W_out  = (const float*)d_in[11];
    float* out = (float*)d_out;
    float* ws  = (float*)d_ws;

    unsigned short* xnb   = (unsigned short*)ws;                  // phase A
    unsigned short* W_inT = (unsigned short*)(ws + 2097152L);
    float* P              = ws;                                   // phase B
    float* Hend           = ws + 2097152L;
    unsigned short* xzb   = (unsigned short*)(ws + 4194304L);
    unsigned short* ubf   = (unsigned short*)(ws + 12582912L);
    float* xdbl  = ws + 16777216L;
    unsigned short* deltab = (unsigned short*)(ws + 17301504L);
    unsigned short* W_xpT = (unsigned short*)(ws + 25690112L);
    unsigned short* W_dtT = (unsigned short*)(ws + 25821184L);
    unsigned short* dtb   = (unsigned short*)(ws + 25886720L);
    unsigned short* ybf   = (unsigned short*)(ws + 26017792L);
    unsigned short* W_outT= (unsigned short*)(ws + 30212096L);
    float* part           = ws + 31260672L;

    // 1. LayerNorm -> bf16
    ln_kernel<<<ROWS, 256, 0, stream>>>(x, gamma, beta, xnb);
    // 2. all weight transposes -> bf16 [N][K]
    transpose_all<<<6528, 256, 0, stream>>>(W_in, W_inT, W_xp, W_xpT,
                                            W_dt, W_dtT, W_out, W_outT);
    // 3. xz = xn @ W_in   (M=4096, N=4096, K=1024) -> bf16
    gemm_bf16<0,1><<<dim3(32, 32), 256, 0, stream>>>(xnb, W_inT, xzb, nullptr, 4096, 4096, 1024);
    // 4. conv + silu -> ubf
    conv_silu<<<8192, 256, 0, stream>>>(xzb, conv_w, conv_b, ubf);
    // 5. xdbl = u @ W_xproj: split-K x8 partials + reduce (also emits dtb bf16)
    gemm_bf16<3,0><<<dim3(1, 32, 8), 256, 0, stream>>>(ubf, W_xpT, part, nullptr, 4096, 128, 2048);
    reduce_xdbl<<<512, 256, 0, stream>>>(part, xdbl, dtb);
    // 6. delta = softplus(dt @ W_dt + b_dt) -> bf16  (M=4096, N=2048, K=64)
    gemm_bf16<2,1><<<dim3(16, 32), 256, 0, stream>>>(dtb, W_dtT, deltab, b_dt, 4096, 2048, 64);
    // 7. chunked parallel scan
    scan_p1<<<dim3(DINNER/256, NC, 2), 256, 0, stream>>>(ubf, deltab, xdbl, A_log, P, Hend);
    scan_p2<<<256, 256, 0, stream>>>(P, Hend);
    scan_p3<<<dim3(DINNER/256, NC, 2), 256, 0, stream>>>(ubf, deltab, xdbl, A_log, Dp, Hend, xzb, ybf);
    // 8. out = x + y @ W_out  (M=4096, N=1024, K=2048)
    gemm_bf16<1,0><<<dim3(8, 32), 256, 0, stream>>>(ybf, W_outT, out, x, 4096, 1024, 2048);
}

// Round 9
// 263.885 us; speedup vs baseline: 7.5988x; 1.0337x over previous
//
#include <hip/hip_runtime.h>
#include <hip/hip_bf16.h>

// B=2, L=2048, DIM=1024, D_INNER=2048, DT_RANK=64, D_STATE=16, D_CONV=4
// ws layout (float offsets), total 35,454,976 floats = 141.8 MB (no live overlaps):
//   region0 @0 (4,194,304): phase A: xnb bf16[4096][1024] @0, W_inT bf16[4096][1024] @2097152
//                           phase B (after GEMM-in): P fp32 @0, Hend fp32 @2097152
//   xzb   @  4194304: bf16 [4096][4096] (8,388,608 fl)   -> 12582912
//   ubf   @ 12582912: bf16 [4096][2048] (4,194,304 fl)   -> 16777216
//   xdbl  @ 16777216: fp32 [4096][128]  (524,288 fl)     -> 17301504  (dt|B|C|pad)
//   delta @ 17301504: bf16 [4096][2048] (region oversized; 2,097,152 fl used)
//   W_xpT @ 25690112: bf16 [128][2048]
//   W_dtT @ 25821184: bf16 [2048][64]
//   dtb   @ 25886720: bf16 [4096][64]
//   ybf   @ 26017792: bf16 [4096][2048]
//   W_outT@ 30212096: bf16 [1024][2048]
//   part  @ 31260672: fp32 [8][4096][128] -> 35454976

#define ROWS 4096
#define DIM 1024
#define DINNER 2048
#define LSEQ 2048
#define NC 32
#define CL 64

typedef short short8_t __attribute__((ext_vector_type(8)));
typedef float f32x4_t __attribute__((ext_vector_type(4)));

__device__ __forceinline__ unsigned short f2bf(float f) {
    union { float f; unsigned u; } v; v.f = f;
    unsigned r = v.u + 0x7fffu + ((v.u >> 16) & 1u);
    return (unsigned short)(r >> 16);
}
__device__ __forceinline__ float bf2f(unsigned short b) {
    union { unsigned u; float f; } v; v.u = ((unsigned)b) << 16;
    return v.f;
}

// Fused: blocks 0..4095 = LayerNorm rows; blocks 4096.. = the 4 weight transposes.
__global__ __launch_bounds__(256) void prep_kernel(
    const float* __restrict__ x, const float* __restrict__ gamma,
    const float* __restrict__ beta, unsigned short* __restrict__ xnb,
    const float* __restrict__ W_in,  unsigned short* __restrict__ W_inT,
    const float* __restrict__ W_xp,  unsigned short* __restrict__ W_xpT,
    const float* __restrict__ W_dt,  unsigned short* __restrict__ W_dtT,
    const float* __restrict__ W_out, unsigned short* __restrict__ W_outT)
{
    __shared__ float tile[32][33];
    __shared__ float ss[8], ssq[8];
    int b = blockIdx.x;
    if (b < 4096) {
        const int row = b, tid = threadIdx.x;
        float4 v = ((const float4*)(x + (long)row * DIM))[tid];
        float s  = v.x + v.y + v.z + v.w;
        float sq = v.x*v.x + v.y*v.y + v.z*v.z + v.w*v.w;
        #pragma unroll
        for (int off = 32; off > 0; off >>= 1) {
            s  += __shfl_down(s,  off, 64);
            sq += __shfl_down(sq, off, 64);
        }
        const int wid = tid >> 6, lane = tid & 63;
        if (lane == 0) { ss[wid] = s; ssq[wid] = sq; }
        __syncthreads();
        if (tid == 0) {
            float S = 0.f, SQ = 0.f;
            for (int w = 0; w < 4; ++w) { S += ss[w]; SQ += ssq[w]; }
            float mu  = S / (float)DIM;
            float var = SQ / (float)DIM - mu * mu;
            ss[4]  = mu;
            ssq[4] = rsqrtf(var + 1e-5f);
        }
        __syncthreads();
        const float mu = ss[4], rs = ssq[4];
        float4 g = ((const float4*)gamma)[tid];
        float4 bb = ((const float4*)beta)[tid];
        ushort4 o;
        o.x = f2bf((v.x - mu) * rs * g.x + bb.x);
        o.y = f2bf((v.y - mu) * rs * g.y + bb.y);
        o.z = f2bf((v.z - mu) * rs * g.z + bb.z);
        o.w = f2bf((v.w - mu) * rs * g.w + bb.w);
        *(ushort4*)(xnb + (long)row * DIM + tid * 4) = o;
        return;
    }
    b -= 4096;
    const float* in; unsigned short* out; int R, C, tx, ty;
    if (b < 4096)      { in = W_in;  out = W_inT;  R = 1024; C = 4096; int t = b;        tx = t & 127; ty = t >> 7; }
    else if (b < 4352) { in = W_xp;  out = W_xpT;  R = 2048; C = 96;   int t = b - 4096; tx = t & 3;   ty = t >> 2; }
    else if (b < 4480) { in = W_dt;  out = W_dtT;  R = 64;   C = 2048; int t = b - 4352; tx = t & 63;  ty = t >> 6; }
    else               { in = W_out; out = W_outT; R = 2048; C = 1024; int t = b - 4480; tx = t & 31;  ty = t >> 5; }
    const int c0 = tx * 32, r0 = ty * 32;
    const int lx = threadIdx.x & 31, ly = threadIdx.x >> 5;
    #pragma unroll
    for (int i = 0; i < 4; ++i) {
        int r = r0 + ly + i * 8;
        int c = c0 + lx;
        tile[ly + i * 8][lx] = (c < C) ? in[(long)r * C + c] : 0.f;
    }
    __syncthreads();
    #pragma unroll
    for (int i = 0; i < 4; ++i) {
        int c = c0 + ly + i * 8;
        int r = r0 + lx;
        out[(long)c * R + r] = f2bf(tile[lx][ly + i * 8]);
    }
}

// C[M,N] = A[M,K] @ Bt[N,K]^T. bf16 in. BMx128 tile (BM=128 or 64), BK=32, 4 waves.
// 2-buffer counted-vmcnt pipeline (never drain-0 mid-loop), raw s_barrier, XOR swizzle.
// MODE 0: C=acc. MODE 1: C=acc+aux[row*N+col]. MODE 2: C=softplus(acc+aux[col]).
// MODE 3: split-K partials (grid.z = 8 slices, fp32). OUTBF: 1 -> bf16 out.
template <int MODE, int OUTBF, int BM>
__global__ __launch_bounds__(256) void gemm_bf16(
    const unsigned short* __restrict__ A,
    const unsigned short* __restrict__ Bt,
    void* __restrict__ Cv,
    const float* __restrict__ aux,
    int M, int N, int K)
{
    constexpr int NFN = (BM == 128) ? 4 : 2;   // n-frags per wave
    constexpr int CW  = (BM == 128) ? 64 : 32; // per-wave col width
    __shared__ __align__(16) unsigned short As[2][BM * 32];
    __shared__ __align__(16) unsigned short Bs[2][128 * 32];
    const int tid  = threadIdx.x;
    const int wave = tid >> 6, lane = tid & 63;
    const int wr = (BM == 128) ? (wave >> 1) : 0;
    const int wc = (BM == 128) ? (wave & 1) : wave;
    const int l15 = lane & 15, l4 = lane >> 4;
    const long row0 = (long)blockIdx.y * BM;
    const long col0 = (long)blockIdx.x * 128;
    int Koff = 0, Klen = K;
    if (MODE == 3) { Klen = K >> 3; Koff = blockIdx.z * Klen; }

    f32x4_t acc[4][NFN];
    #pragma unroll
    for (int m = 0; m < 4; ++m)
        #pragma unroll
        for (int n = 0; n < NFN; ++n)
            acc[m][n] = (f32x4_t){0.f, 0.f, 0.f, 0.f};

    // Source-chunk XOR swizzle (LDS dest linear per gload_lds; read applies same XOR).
    const int srow = tid >> 2;
    const int scol = ((tid & 3) ^ (srow & 3)) * 8;
    const unsigned short* Ag = A  + (row0 + srow) * (long)K + Koff + scol;
    const unsigned short* Bg = Bt + (col0 + srow) * (long)K + Koff + scol;

    auto stage = [&](int buf, int k0) {
        unsigned short* AsW = &As[buf][wave * 512];
        unsigned short* BsW = &Bs[buf][wave * 512];
        __builtin_amdgcn_global_load_lds(
            (const __attribute__((address_space(1))) void*)(Ag + k0),
            (__attribute__((address_space(3))) void*)AsW, 16, 0, 0);
        if (BM == 128)
            __builtin_amdgcn_global_load_lds(
                (const __attribute__((address_space(1))) void*)(Ag + 64 * (long)K + k0),
                (__attribute__((address_space(3))) void*)(AsW + 2048), 16, 0, 0);
        __builtin_amdgcn_global_load_lds(
            (const __attribute__((address_space(1))) void*)(Bg + k0),
            (__attribute__((address_space(3))) void*)BsW, 16, 0, 0);
        __builtin_amdgcn_global_load_lds(
            (const __attribute__((address_space(1))) void*)(Bg + 64 * (long)K + k0),
            (__attribute__((address_space(3))) void*)(BsW + 2048), 16, 0, 0);
    };
    const int rchunk = (l4 ^ (l15 & 3)) * 8;   // swizzled read chunk (ushorts)
    auto compute = [&](int buf) {
        const unsigned short* Ab = As[buf];
        const unsigned short* Bb = Bs[buf];
        short8_t af[4], bf[NFN];
        #pragma unroll
        for (int m = 0; m < 4; ++m)
            af[m] = *(const short8_t*)&Ab[(wr * 64 + m * 16 + l15) * 32 + rchunk];
        #pragma unroll
        for (int n = 0; n < NFN; ++n)
            bf[n] = *(const short8_t*)&Bb[(wc * CW + n * 16 + l15) * 32 + rchunk];
        __builtin_amdgcn_s_setprio(1);
        #pragma unroll
        for (int m = 0; m < 4; ++m)
            #pragma unroll
            for (int n = 0; n < NFN; ++n)
                acc[m][n] = __builtin_amdgcn_mfma_f32_16x16x32_bf16(
                    af[m], bf[n], acc[m][n], 0, 0, 0);
        __builtin_amdgcn_s_setprio(0);
    };

    const int nt = Klen >> 5;           // >= 1 at every call site
    stage(0, 0);
    if (nt > 1) stage(1, 32);
    int cur = 0;
    for (int t = 0; t < nt; ++t) {
        // 4 (BM=128) or 3 (BM=64) loads per wave per stage; wait until tile t's
        // loads landed, leaving tile t+1's in flight (counted vmcnt).
        if (t + 1 < nt) {
            if constexpr (BM == 128) asm volatile("s_waitcnt vmcnt(4)" ::: "memory");
            else                     asm volatile("s_waitcnt vmcnt(3)" ::: "memory");
        } else {
            asm volatile("s_waitcnt vmcnt(0)" ::: "memory");
        }
        __builtin_amdgcn_s_barrier();           // all waves' tile-t slices resident
        __builtin_amdgcn_sched_barrier(0);      // no ds_read hoist above barrier
        compute(cur);
        __builtin_amdgcn_s_barrier();           // all waves done reading buf[cur]
        if (t + 2 < nt) stage(cur, (t + 2) * 32);
        cur ^= 1;
    }

    float* Cf = (float*)Cv;
    unsigned short* Cb = (unsigned short*)Cv;
    if (MODE == 3) Cf += (long)blockIdx.z * M * (long)N;
    #pragma unroll
    for (int m = 0; m < 4; ++m) {
        #pragma unroll
        for (int n = 0; n < NFN; ++n) {
            #pragma unroll
            for (int r = 0; r < 4; ++r) {
                long row = row0 + wr * 64 + m * 16 + l4 * 4 + r;
                long col = col0 + wc * CW + n * 16 + l15;
                float v = acc[m][n][r];
                if (MODE == 1) v += aux[row * (long)N + col];
                if (MODE == 2) {
                    v += aux[col];
                    v = (v > 20.f) ? v : log1pf(__expf(v));
                }
                if (OUTBF) Cb[row * (long)N + col] = f2bf(v);
                else       Cf[row * (long)N + col] = v;
            }
        }
    }
}

// xdbl = sum over 8 split-K partials; also emit dtb = bf16(dt cols 0:64).
__global__ __launch_bounds__(256) void reduce_xdbl(
    const float* __restrict__ part, float* __restrict__ xdbl,
    unsigned short* __restrict__ dtb)
{
    const int i = blockIdx.x * 256 + threadIdx.x;   // 0..131071 (float4 units)
    const int r = i >> 5, c4 = (i & 31) * 4;
    float4 s = {0.f, 0.f, 0.f, 0.f};
    #pragma unroll
    for (int k = 0; k < 8; ++k) {
        float4 v = *(const float4*)(part + (long)k * 524288 + (long)r * 128 + c4);
        s.x += v.x; s.y += v.y; s.z += v.z; s.w += v.w;
    }
    *(float4*)(xdbl + (long)r * 128 + c4) = s;
    if (c4 < 64) {
        ushort4 o = { f2bf(s.x), f2bf(s.y), f2bf(s.z), f2bf(s.w) };
        *(ushort4*)(dtb + (long)r * 64 + c4) = o;
    }
}

// u = silu(depthwise causal conv(xzb[:, :2048]) + cb) -> bf16
__global__ __launch_bounds__(256) void conv_silu(
    const unsigned short* __restrict__ xzb, const float* __restrict__ cw,
    const float* __restrict__ cb, unsigned short* __restrict__ ubf)
{
    const int t = blockIdx.x * 256 + threadIdx.x;
    const int dq = t & 511;
    const int l  = (t >> 9) & 2047;
    const int b  = t >> 20;
    const int d  = dq * 4;
    const float4* w4 = (const float4*)(cw + (long)d * 4);
    float4 w0 = w4[0], w1 = w4[1], w2 = w4[2], w3 = w4[3];
    const float* wr[4] = { (const float*)&w0, (const float*)&w1,
                           (const float*)&w2, (const float*)&w3 };
    float4 bias = *(const float4*)(cb + d);
    float acc0 = bias.x, acc1 = bias.y, acc2 = bias.z, acc3 = bias.w;
    const unsigned short* base = xzb + ((long)b * LSEQ) * 4096 + d;
    #pragma unroll
    for (int k = 0; k < 4; ++k) {
        int ls = l - 3 + k;
        if (ls >= 0) {
            ushort4 tv = *(const ushort4*)(base + (long)ls * 4096);
            acc0 = fmaf(wr[0][k], bf2f(tv.x), acc0);
            acc1 = fmaf(wr[1][k], bf2f(tv.y), acc1);
            acc2 = fmaf(wr[2][k], bf2f(tv.z), acc2);
            acc3 = fmaf(wr[3][k], bf2f(tv.w), acc3);
        }
    }
    ushort4 o;
    o.x = f2bf(acc0 / (1.f + __expf(-acc0)));
    o.y = f2bf(acc1 / (1.f + __expf(-acc1)));
    o.z = f2bf(acc2 / (1.f + __expf(-acc2)));
    o.w = f2bf(acc3 / (1.f + __expf(-acc3)));
    *(ushort4*)(ubf + ((long)b * LSEQ + l) * DINNER + d) = o;
}

// Phase 1: per (b, chunk, d): local scan from h=0; write P (cumprod a) and Hend.
__global__ __launch_bounds__(256) void scan_p1(
    const unsigned short* __restrict__ ubf, const unsigned short* __restrict__ delta,
    const float* __restrict__ xdbl, const float* __restrict__ A_log,
    float* __restrict__ P, float* __restrict__ Hend)
{
    __shared__ float bsm[CL * 16];
    const int d = blockIdx.x * 256 + threadIdx.x;
    const int c = blockIdx.y;
    const int b = blockIdx.z;
    const long rowbase = (long)b * LSEQ + (long)c * CL;
    for (int i = threadIdx.x; i < CL * 16; i += 256) {
        int t = i >> 4, s = i & 15;
        bsm[i] = xdbl[(rowbase + t) * 128 + 64 + s];
    }
    __syncthreads();
    float A[16];
    #pragma unroll
    for (int s = 0; s < 16; ++s) A[s] = -__expf(A_log[(long)d * 16 + s]);
    float h[16], p[16];
    #pragma unroll
    for (int s = 0; s < 16; ++s) { h[s] = 0.f; p[s] = 1.f; }
    const unsigned short* ub = ubf + rowbase * DINNER + d;
    const unsigned short* db = delta + rowbase * DINNER + d;
    for (int t = 0; t < CL; ++t) {
        float dt = bf2f(db[(long)t * DINNER]);
        float du = dt * bf2f(ub[(long)t * DINNER]);
        const float* bv = &bsm[t * 16];
        #pragma unroll
        for (int s = 0; s < 16; ++s) {
            float a = __expf(dt * A[s]);
            p[s] *= a;
            h[s] = fmaf(h[s], a, du * bv[s]);
        }
    }
    const long o = (((long)b * NC + c) * DINNER + d) * 16;
    #pragma unroll
    for (int q = 0; q < 4; ++q) {
        *(float4*)(P    + o + q*4) = make_float4(p[q*4],p[q*4+1],p[q*4+2],p[q*4+3]);
        *(float4*)(Hend + o + q*4) = make_float4(h[q*4],h[q*4+1],h[q*4+2],h[q*4+3]);
    }
}

// Phase 2: sequential over chunks; Hend -> Hin in place.
__global__ __launch_bounds__(256) void scan_p2(
    const float* __restrict__ P, float* __restrict__ H)
{
    const int idx = blockIdx.x * 256 + threadIdx.x;
    const int b = idx >> 15;
    const int rest = idx & 32767;
    float carry = 0.f;
    for (int c = 0; c < NC; ++c) {
        const long a = ((long)(b * NC + c) << 15) + rest;
        float tmp = H[a];
        float pp  = P[a];
        H[a] = carry;
        carry = fmaf(carry, pp, tmp);
    }
}

// Phase 3: re-run local scan from Hin; y + D*u, gate silu(z); write ybf (bf16).
__global__ __launch_bounds__(256) void scan_p3(
    const unsigned short* __restrict__ ubf, const unsigned short* __restrict__ delta,
    const float* __restrict__ xdbl, const float* __restrict__ A_log,
    const float* __restrict__ Dp, const float* __restrict__ Hin,
    const unsigned short* __restrict__ xzb, unsigned short* __restrict__ ybf)
{
    __shared__ float bcs[CL * 32];
    const int d = blockIdx.x * 256 + threadIdx.x;
    const int c = blockIdx.y;
    const int b = blockIdx.z;
    const long rowbase = (long)b * LSEQ + (long)c * CL;
    for (int i = threadIdx.x; i < CL * 32; i += 256) {
        int t = i >> 5, s = i & 31;
        bcs[i] = xdbl[(rowbase + t) * 128 + 64 + s];
    }
    __syncthreads();
    float A[16];
    #pragma unroll
    for (int s = 0; s < 16; ++s) A[s] = -__expf(A_log[(long)d * 16 + s]);
    float h[16];
    const long o = (((long)b * NC + c) * DINNER + d) * 16;
    #pragma unroll
    for (int q = 0; q < 4; ++q) {
        float4 hv = *(const float4*)(Hin + o + q*4);
        h[q*4] = hv.x; h[q*4+1] = hv.y; h[q*4+2] = hv.z; h[q*4+3] = hv.w;
    }
    const float Dd = Dp[d];
    const unsigned short* ub = ubf + rowbase * DINNER + d;
    const unsigned short* db = delta + rowbase * DINNER + d;
    const unsigned short* zz = xzb + rowbase * 4096 + 2048 + d;
    for (int t = 0; t < CL; ++t) {
        float dt = bf2f(db[(long)t * DINNER]);
        float ut = bf2f(ub[(long)t * DINNER]);
        float zt = bf2f(zz[(long)t * 4096]);
        float du = dt * ut;
        const float* bv = &bcs[t * 32];
        float y = 0.f;
        #pragma unroll
        for (int s = 0; s < 16; ++s) {
            float a = __expf(dt * A[s]);
            h[s] = fmaf(h[s], a, du * bv[s]);
            y = fmaf(h[s], bv[16 + s], y);
        }
        y = fmaf(ut, Dd, y);
        float sig = 1.f / (1.f + __expf(-zt));
        ybf[(rowbase + t) * DINNER + d] = f2bf(y * (zt * sig));
    }
}

extern "C" void kernel_launch(void* const* d_in, const int* in_sizes, int n_in,
                              void* d_out, int out_size, void* d_ws, size_t ws_size,
                              hipStream_t stream) {
    const float* x      = (const float*)d_in[0];
    const float* gamma  = (const float*)d_in[1];
    const float* beta   = (const float*)d_in[2];
    const float* W_in   = (const float*)d_in[3];
    const float* conv_w = (const float*)d_in[4];
    const float* conv_b = (const float*)d_in[5];
    const float* W_xp   = (const float*)d_in[6];
    const float* W_dt   = (const float*)d_in[7];
    const float* b_dt   = (const float*)d_in[8];
    const float* A_log  = (const float*)d_in[9];
    const float* Dp     = (const float*)d_in[10];
    const float* W_out  = (const float*)d_in[11];
    float* out = (float*)d_out;
    float* ws  = (float*)d_ws;

    unsigned short* xnb   = (unsigned short*)ws;                  // phase A
    unsigned short* W_inT = (unsigned short*)(ws + 2097152L);
    float* P              = ws;                                   // phase B
    float* Hend           = ws + 2097152L;
    unsigned short* xzb   = (unsigned short*)(ws + 4194304L);
    unsigned short* ubf   = (unsigned short*)(ws + 12582912L);
    float* xdbl  = ws + 16777216L;
    unsigned short* deltab = (unsigned short*)(ws + 17301504L);
    unsigned short* W_xpT = (unsigned short*)(ws + 25690112L);
    unsigned short* W_dtT = (unsigned short*)(ws + 25821184L);
    unsigned short* dtb   = (unsigned short*)(ws + 25886720L);
    unsigned short* ybf   = (unsigned short*)(ws + 26017792L);
    unsigned short* W_outT= (unsigned short*)(ws + 30212096L);
    float* part           = ws + 31260672L;

    // 1. LayerNorm + all weight transposes (fused)
    prep_kernel<<<10624, 256, 0, stream>>>(x, gamma, beta, xnb,
                                           W_in, W_inT, W_xp, W_xpT,
                                           W_dt, W_dtT, W_out, W_outT);
    // 2. xz = xn @ W_in   (M=4096, N=4096, K=1024) -> bf16
    gemm_bf16<0,1,128><<<dim3(32, 32), 256, 0, stream>>>(xnb, W_inT, xzb, nullptr, 4096, 4096, 1024);
    // 3. conv + silu -> ubf
    conv_silu<<<8192, 256, 0, stream>>>(xzb, conv_w, conv_b, ubf);
    // 4. xdbl = u @ W_xproj: split-K x8 partials + reduce (also emits dtb bf16)
    gemm_bf16<3,0,128><<<dim3(1, 32, 8), 256, 0, stream>>>(ubf, W_xpT, part, nullptr, 4096, 128, 2048);
    reduce_xdbl<<<512, 256, 0, stream>>>(part, xdbl, dtb);
    // 5. delta = softplus(dt @ W_dt + b_dt) -> bf16  (M=4096, N=2048, K=64)
    gemm_bf16<2,1,128><<<dim3(16, 32), 256, 0, stream>>>(dtb, W_dtT, deltab, b_dt, 4096, 2048, 64);
    // 6. chunked parallel scan
    scan_p1<<<dim3(DINNER/256, NC, 2), 256, 0, stream>>>(ubf, deltab, xdbl, A_log, P, Hend);
    scan_p2<<<256, 256, 0, stream>>>(P, Hend);
    scan_p3<<<dim3(DINNER/256, NC, 2), 256, 0, stream>>>(ubf, deltab, xdbl, A_log, Dp, Hend, xzb, ybf);
    // 7. out = x + y @ W_out  (M=4096, N=1024, K=2048), BM=64 tile -> 512 blocks
    gemm_bf16<1,0,64><<<dim3(8, 64), 256, 0, stream>>>(ybf, W_outT, out, x, 4096, 1024, 2048);
}